// Round 1
// baseline (455.966 us; speedup 1.0000x reference)
//
#include <hip/hip_runtime.h>
#include <hip/hip_bf16.h>

#define HD 128   // hidden/feature dim
#define NL 7     // label dim

// ---------------- CSR build ----------------

__global__ void k_count(const int* __restrict__ dst, int E, int* __restrict__ counts) {
    int i = blockIdx.x * blockDim.x + threadIdx.x;
    if (i < E) atomicAdd(&counts[dst[i]], 1);
}

__global__ void k_dinv(const int* __restrict__ counts, float* __restrict__ dinv, int n) {
    int v = blockIdx.x * blockDim.x + threadIdx.x;
    if (v < n) dinv[v] = 1.0f / sqrtf((float)(counts[v] + 1));  // +1 self loop, deg>=1
}

__global__ __launch_bounds__(1024) void k_scan(const int* __restrict__ counts,
                                               int* __restrict__ row_start, int n) {
    __shared__ int part[1024];
    int t = threadIdx.x;
    int chunk = (n + 1023) >> 10;
    int lo = t * chunk, hi = min(lo + chunk, n);
    int s = 0;
    for (int i = lo; i < hi; ++i) s += counts[i];
    part[t] = s;
    __syncthreads();
    for (int off = 1; off < 1024; off <<= 1) {
        int v = (t >= off) ? part[t - off] : 0;
        __syncthreads();
        part[t] += v;
        __syncthreads();
    }
    int base = part[t] - s;  // exclusive prefix for this chunk
    for (int i = lo; i < hi; ++i) { row_start[i] = base; base += counts[i]; }
    if (t == 0) row_start[n] = part[1023];
}

__global__ void k_fill(const int* __restrict__ src, const int* __restrict__ dst, int E,
                       const int* __restrict__ row_start, int* __restrict__ cursor,
                       int* __restrict__ col) {
    int i = blockIdx.x * blockDim.x + threadIdx.x;
    if (i < E) {
        int d = dst[i];
        int pos = row_start[d] + atomicAdd(&cursor[d], 1);
        col[pos] = src[i];
    }
}

// ---------------- GEMM: Y[n,128] = X[n,128] @ W[128,128] ----------------
// 64-row tile in LDS, W rows streamed from global (64KB -> L1/L2 resident).
// 256 threads: 32 col-threads (float4) x 8 row-groups, each thread 8 rows x 4 cols.

__global__ __launch_bounds__(256) void k_gemm128(const float* __restrict__ X,
                                                 const float* __restrict__ W,
                                                 float* __restrict__ Y, int n) {
    __shared__ float xs[64][HD];
    int tid = threadIdx.x;
    int row0 = blockIdx.x * 64;

    // stage x tile: 8192 floats = 2048 float4, 8 per thread, coalesced
    #pragma unroll
    for (int j = 0; j < 8; ++j) {
        int f4 = tid + j * 256;        // 0..2047
        int r = f4 >> 5;               // 32 float4 per row
        int c = (f4 & 31) * 4;
        int gr = row0 + r;
        float4 v = make_float4(0.f, 0.f, 0.f, 0.f);
        if (gr < n) v = *(const float4*)&X[(size_t)gr * HD + c];
        *(float4*)&xs[r][c] = v;
    }
    __syncthreads();

    int cg = (tid & 31) * 4;       // this thread's 4 output cols
    int rg = (tid >> 5) * 8;       // this thread's 8 rows (tile-local)

    float4 acc[8];
    #pragma unroll
    for (int i = 0; i < 8; ++i) acc[i] = make_float4(0.f, 0.f, 0.f, 0.f);

    for (int k = 0; k < HD; k += 4) {
        float4 w0 = *(const float4*)&W[(size_t)(k + 0) * HD + cg];
        float4 w1 = *(const float4*)&W[(size_t)(k + 1) * HD + cg];
        float4 w2 = *(const float4*)&W[(size_t)(k + 2) * HD + cg];
        float4 w3 = *(const float4*)&W[(size_t)(k + 3) * HD + cg];
        #pragma unroll
        for (int i = 0; i < 8; ++i) {
            float4 xv = *(const float4*)&xs[rg + i][k];
            acc[i].x = fmaf(xv.x, w0.x, acc[i].x);
            acc[i].y = fmaf(xv.x, w0.y, acc[i].y);
            acc[i].z = fmaf(xv.x, w0.z, acc[i].z);
            acc[i].w = fmaf(xv.x, w0.w, acc[i].w);
            acc[i].x = fmaf(xv.y, w1.x, acc[i].x);
            acc[i].y = fmaf(xv.y, w1.y, acc[i].y);
            acc[i].z = fmaf(xv.y, w1.z, acc[i].z);
            acc[i].w = fmaf(xv.y, w1.w, acc[i].w);
            acc[i].x = fmaf(xv.z, w2.x, acc[i].x);
            acc[i].y = fmaf(xv.z, w2.y, acc[i].y);
            acc[i].z = fmaf(xv.z, w2.z, acc[i].z);
            acc[i].w = fmaf(xv.z, w2.w, acc[i].w);
            acc[i].x = fmaf(xv.w, w3.x, acc[i].x);
            acc[i].y = fmaf(xv.w, w3.y, acc[i].y);
            acc[i].z = fmaf(xv.w, w3.z, acc[i].z);
            acc[i].w = fmaf(xv.w, w3.w, acc[i].w);
        }
    }

    #pragma unroll
    for (int i = 0; i < 8; ++i) {
        int gr = row0 + rg + i;
        if (gr < n) *(float4*)&Y[(size_t)gr * HD + cg] = acc[i];
    }
}

// ---------------- Aggregation: out[v] = relu( sum_{s in N(v)} h[s]*dinv[s]*dinv[v]
//                                              + h[v]*dinv[v]^2 + bias ) ----------------
// One wave per node; each lane owns 2 features (float2). 4-edge unroll for MLP.

__global__ __launch_bounds__(256) void k_agg(const float* __restrict__ hin,
                                             const float* __restrict__ dinv,
                                             const int* __restrict__ row_start,
                                             const int* __restrict__ col,
                                             const float* __restrict__ bias,
                                             float* __restrict__ hout, int n) {
    int wave = threadIdx.x >> 6;
    int lane = threadIdx.x & 63;
    int v = blockIdx.x * 4 + wave;
    if (v >= n) return;

    float dv = dinv[v];
    int f = lane * 2;
    float2 acc = *(const float2*)(hin + (size_t)v * HD + f);
    float selfw = dv * dv;
    acc.x *= selfw; acc.y *= selfw;

    int e = row_start[v], e1 = row_start[v + 1];
    for (; e + 4 <= e1; e += 4) {
        int s0 = col[e], s1 = col[e + 1], s2 = col[e + 2], s3 = col[e + 3];
        float w0 = dinv[s0] * dv, w1 = dinv[s1] * dv, w2 = dinv[s2] * dv, w3 = dinv[s3] * dv;
        float2 a0 = *(const float2*)(hin + (size_t)s0 * HD + f);
        float2 a1 = *(const float2*)(hin + (size_t)s1 * HD + f);
        float2 a2 = *(const float2*)(hin + (size_t)s2 * HD + f);
        float2 a3 = *(const float2*)(hin + (size_t)s3 * HD + f);
        acc.x = fmaf(a0.x, w0, acc.x); acc.y = fmaf(a0.y, w0, acc.y);
        acc.x = fmaf(a1.x, w1, acc.x); acc.y = fmaf(a1.y, w1, acc.y);
        acc.x = fmaf(a2.x, w2, acc.x); acc.y = fmaf(a2.y, w2, acc.y);
        acc.x = fmaf(a3.x, w3, acc.x); acc.y = fmaf(a3.y, w3, acc.y);
    }
    for (; e < e1; ++e) {
        int s = col[e];
        float w = dinv[s] * dv;
        float2 a = *(const float2*)(hin + (size_t)s * HD + f);
        acc.x = fmaf(a.x, w, acc.x); acc.y = fmaf(a.y, w, acc.y);
    }

    float2 b = *(const float2*)(bias + f);
    float2 o;
    o.x = fmaxf(acc.x + b.x, 0.f);
    o.y = fmaxf(acc.y + b.y, 0.f);
    *(float2*)(hout + (size_t)v * HD + f) = o;
}

// ---------------- Mean-pool over sorted batch + FC ----------------

__global__ __launch_bounds__(128) void k_pool(const float* __restrict__ h,
                                              const int* __restrict__ batch,
                                              const float* __restrict__ Wfc,
                                              const float* __restrict__ bfc,
                                              float* __restrict__ out, int n) {
    int g = blockIdx.x;
    int t = threadIdx.x;   // 128 threads, one feature each
    __shared__ int slo, shi;
    if (t == 0) {
        int lo = 0, hi = n;
        while (lo < hi) { int m = (lo + hi) >> 1; if (batch[m] < g) lo = m + 1; else hi = m; }
        slo = lo;
        lo = 0; hi = n;
        while (lo < hi) { int m = (lo + hi) >> 1; if (batch[m] < g + 1) lo = m + 1; else hi = m; }
        shi = lo;
    }
    __syncthreads();
    int lo = slo, hi = shi;
    float sum = 0.f;
    for (int i = lo; i < hi; ++i) sum += h[(size_t)i * HD + t];
    float cnt = (float)(hi - lo);
    __shared__ float sp[HD];
    sp[t] = sum / fmaxf(cnt, 1.f);
    __syncthreads();
    if (t < NL) {
        float o = bfc[t];
        for (int k = 0; k < HD; ++k) o = fmaf(sp[k], Wfc[k * NL + t], o);
        out[g * NL + t] = o;
    }
}

// ---------------- launch ----------------

extern "C" void kernel_launch(void* const* d_in, const int* in_sizes, int n_in,
                              void* d_out, int out_size, void* d_ws, size_t ws_size,
                              hipStream_t stream) {
    const float* x    = (const float*)d_in[0];
    const int*   ei   = (const int*)d_in[1];
    const int*   batch= (const int*)d_in[2];
    const float* W1   = (const float*)d_in[3];
    const float* b1   = (const float*)d_in[4];
    const float* W2   = (const float*)d_in[5];
    const float* b2   = (const float*)d_in[6];
    const float* Wfc  = (const float*)d_in[7];
    const float* bfc  = (const float*)d_in[8];
    float* out = (float*)d_out;

    int n = in_sizes[0] / HD;       // 50000
    int E = in_sizes[1] / 2;        // 800000
    int G = out_size / NL;          // 128
    const int* srcp = ei;
    const int* dstp = ei + E;

    char* ws = (char*)d_ws;
    auto align256 = [](size_t v) { return (v + 255) & ~(size_t)255; };
    size_t o = 0;
    int*   counts    = (int*)(ws + o); o = align256(o + (size_t)n * 4);
    int*   cursor    = (int*)(ws + o); o = align256(o + (size_t)n * 4);
    int*   row_start = (int*)(ws + o); o = align256(o + (size_t)(n + 1) * 4);
    float* dinv      = (float*)(ws + o); o = align256(o + (size_t)n * 4);
    int*   col       = (int*)(ws + o); o = align256(o + (size_t)E * 4);
    float* tmp       = (float*)(ws + o); o = align256(o + (size_t)n * HD * 4);
    float* hbuf      = (float*)(ws + o); o = align256(o + (size_t)n * HD * 4);

    hipMemsetAsync(counts, 0, (size_t)n * 4, stream);
    hipMemsetAsync(cursor, 0, (size_t)n * 4, stream);

    k_count<<<(E + 255) / 256, 256, 0, stream>>>(dstp, E, counts);
    k_dinv <<<(n + 255) / 256, 256, 0, stream>>>(counts, dinv, n);
    k_scan <<<1, 1024, 0, stream>>>(counts, row_start, n);
    k_fill <<<(E + 255) / 256, 256, 0, stream>>>(srcp, dstp, E, row_start, cursor, col);

    k_gemm128<<<(n + 63) / 64, 256, 0, stream>>>(x, W1, tmp, n);
    k_agg    <<<(n + 3) / 4, 256, 0, stream>>>(tmp, dinv, row_start, col, b1, hbuf, n);
    k_gemm128<<<(n + 63) / 64, 256, 0, stream>>>(hbuf, W2, tmp, n);
    k_agg    <<<(n + 3) / 4, 256, 0, stream>>>(tmp, dinv, row_start, col, b2, hbuf, n);

    k_pool<<<G, 128, 0, stream>>>(hbuf, batch, Wfc, bfc, out, n);
}

// Round 2
// 422.610 us; speedup vs baseline: 1.0789x; 1.0789x over previous
//
#include <hip/hip_runtime.h>
#include <hip/hip_bf16.h>

#define HD 128   // hidden/feature dim
#define NL 7     // label dim

// ---------------- CSR build ----------------

__global__ void k_count(const int* __restrict__ dst, int E, int* __restrict__ counts) {
    int i = blockIdx.x * blockDim.x + threadIdx.x;
    if (i < E) atomicAdd(&counts[dst[i]], 1);
}

__global__ void k_dinv(const int* __restrict__ counts, float* __restrict__ dinv, int n) {
    int v = blockIdx.x * blockDim.x + threadIdx.x;
    if (v < n) dinv[v] = 1.0f / sqrtf((float)(counts[v] + 1));  // +1 self loop, deg>=1
}

__global__ __launch_bounds__(1024) void k_scan(const int* __restrict__ counts,
                                               int* __restrict__ row_start, int n) {
    __shared__ int part[1024];
    int t = threadIdx.x;
    int chunk = (n + 1023) >> 10;
    int lo = t * chunk, hi = min(lo + chunk, n);
    int s = 0;
    for (int i = lo; i < hi; ++i) s += counts[i];
    part[t] = s;
    __syncthreads();
    for (int off = 1; off < 1024; off <<= 1) {
        int v = (t >= off) ? part[t - off] : 0;
        __syncthreads();
        part[t] += v;
        __syncthreads();
    }
    int base = part[t] - s;  // exclusive prefix for this chunk
    for (int i = lo; i < hi; ++i) { row_start[i] = base; base += counts[i]; }
    if (t == 0) row_start[n] = part[1023];
}

__global__ void k_fill(const int* __restrict__ src, const int* __restrict__ dst, int E,
                       const int* __restrict__ row_start, int* __restrict__ cursor,
                       int* __restrict__ col) {
    int i = blockIdx.x * blockDim.x + threadIdx.x;
    if (i < E) {
        int d = dst[i];
        int pos = row_start[d] + atomicAdd(&cursor[d], 1);
        col[pos] = src[i];
    }
}

// ---------------- GEMM: Y[n,128] = X[n,128] @ W[128,128] ----------------
// 64-row tile in LDS, W rows streamed from global (64KB -> L1/L2 resident).
// 256 threads: 32 col-threads (float4) x 8 row-groups, each thread 8 rows x 4 cols.

__global__ __launch_bounds__(256) void k_gemm128(const float* __restrict__ X,
                                                 const float* __restrict__ W,
                                                 float* __restrict__ Y, int n) {
    __shared__ float xs[64][HD];
    int tid = threadIdx.x;
    int row0 = blockIdx.x * 64;

    // stage x tile: 8192 floats = 2048 float4, 8 per thread, coalesced
    #pragma unroll
    for (int j = 0; j < 8; ++j) {
        int f4 = tid + j * 256;        // 0..2047
        int r = f4 >> 5;               // 32 float4 per row
        int c = (f4 & 31) * 4;
        int gr = row0 + r;
        float4 v = make_float4(0.f, 0.f, 0.f, 0.f);
        if (gr < n) v = *(const float4*)&X[(size_t)gr * HD + c];
        *(float4*)&xs[r][c] = v;
    }
    __syncthreads();

    int cg = (tid & 31) * 4;       // this thread's 4 output cols
    int rg = (tid >> 5) * 8;       // this thread's 8 rows (tile-local)

    float4 acc[8];
    #pragma unroll
    for (int i = 0; i < 8; ++i) acc[i] = make_float4(0.f, 0.f, 0.f, 0.f);

    for (int k = 0; k < HD; k += 4) {
        float4 w0 = *(const float4*)&W[(size_t)(k + 0) * HD + cg];
        float4 w1 = *(const float4*)&W[(size_t)(k + 1) * HD + cg];
        float4 w2 = *(const float4*)&W[(size_t)(k + 2) * HD + cg];
        float4 w3 = *(const float4*)&W[(size_t)(k + 3) * HD + cg];
        #pragma unroll
        for (int i = 0; i < 8; ++i) {
            float4 xv = *(const float4*)&xs[rg + i][k];
            acc[i].x = fmaf(xv.x, w0.x, acc[i].x);
            acc[i].y = fmaf(xv.x, w0.y, acc[i].y);
            acc[i].z = fmaf(xv.x, w0.z, acc[i].z);
            acc[i].w = fmaf(xv.x, w0.w, acc[i].w);
            acc[i].x = fmaf(xv.y, w1.x, acc[i].x);
            acc[i].y = fmaf(xv.y, w1.y, acc[i].y);
            acc[i].z = fmaf(xv.y, w1.z, acc[i].z);
            acc[i].w = fmaf(xv.y, w1.w, acc[i].w);
            acc[i].x = fmaf(xv.z, w2.x, acc[i].x);
            acc[i].y = fmaf(xv.z, w2.y, acc[i].y);
            acc[i].z = fmaf(xv.z, w2.z, acc[i].z);
            acc[i].w = fmaf(xv.z, w2.w, acc[i].w);
            acc[i].x = fmaf(xv.w, w3.x, acc[i].x);
            acc[i].y = fmaf(xv.w, w3.y, acc[i].y);
            acc[i].z = fmaf(xv.w, w3.z, acc[i].z);
            acc[i].w = fmaf(xv.w, w3.w, acc[i].w);
        }
    }

    #pragma unroll
    for (int i = 0; i < 8; ++i) {
        int gr = row0 + rg + i;
        if (gr < n) *(float4*)&Y[(size_t)gr * HD + cg] = acc[i];
    }
}

// ---------------- Aggregation: out[v] = relu( sum_{s in N(v)} h[s]*dinv[s]*dinv[v]
//                                              + h[v]*dinv[v]^2 + bias ) ----------------
// One wave per node; each lane owns 2 features (float2). 4-edge unroll for MLP.

__global__ __launch_bounds__(256) void k_agg(const float* __restrict__ hin,
                                             const float* __restrict__ dinv,
                                             const int* __restrict__ row_start,
                                             const int* __restrict__ col,
                                             const float* __restrict__ bias,
                                             float* __restrict__ hout, int n) {
    int wave = threadIdx.x >> 6;
    int lane = threadIdx.x & 63;
    int v = blockIdx.x * 4 + wave;
    if (v >= n) return;

    float dv = dinv[v];
    int f = lane * 2;
    float2 acc = *(const float2*)(hin + (size_t)v * HD + f);
    float selfw = dv * dv;
    acc.x *= selfw; acc.y *= selfw;

    int e = row_start[v], e1 = row_start[v + 1];
    for (; e + 4 <= e1; e += 4) {
        int s0 = col[e], s1 = col[e + 1], s2 = col[e + 2], s3 = col[e + 3];
        float w0 = dinv[s0] * dv, w1 = dinv[s1] * dv, w2 = dinv[s2] * dv, w3 = dinv[s3] * dv;
        float2 a0 = *(const float2*)(hin + (size_t)s0 * HD + f);
        float2 a1 = *(const float2*)(hin + (size_t)s1 * HD + f);
        float2 a2 = *(const float2*)(hin + (size_t)s2 * HD + f);
        float2 a3 = *(const float2*)(hin + (size_t)s3 * HD + f);
        acc.x = fmaf(a0.x, w0, acc.x); acc.y = fmaf(a0.y, w0, acc.y);
        acc.x = fmaf(a1.x, w1, acc.x); acc.y = fmaf(a1.y, w1, acc.y);
        acc.x = fmaf(a2.x, w2, acc.x); acc.y = fmaf(a2.y, w2, acc.y);
        acc.x = fmaf(a3.x, w3, acc.x); acc.y = fmaf(a3.y, w3, acc.y);
    }
    for (; e < e1; ++e) {
        int s = col[e];
        float w = dinv[s] * dv;
        float2 a = *(const float2*)(hin + (size_t)s * HD + f);
        acc.x = fmaf(a.x, w, acc.x); acc.y = fmaf(a.y, w, acc.y);
    }

    float2 b = *(const float2*)(bias + f);
    float2 o;
    o.x = fmaxf(acc.x + b.x, 0.f);
    o.y = fmaxf(acc.y + b.y, 0.f);
    *(float2*)(hout + (size_t)v * HD + f) = o;
}

// ---------------- Mean-pool stage 1: per-chunk segmented partial sums ----------------
// Grid covers nodes in 256-row chunks; 128 threads = one feature per thread.
// batch is sorted, so each chunk spans very few graphs -> few atomic flushes.

#define POOL_ROWS 256

__global__ __launch_bounds__(128) void k_pool_partial(const float* __restrict__ h,
                                                      const int* __restrict__ batch,
                                                      float* __restrict__ sums, int n) {
    __shared__ int bs[POOL_ROWS];
    int t = threadIdx.x;
    int r0 = blockIdx.x * POOL_ROWS;
    int r1 = min(r0 + POOL_ROWS, n);
    int cnt = r1 - r0;
    // stage batch ids for this chunk
    for (int i = t; i < cnt; i += 128) bs[i] = batch[r0 + i];
    __syncthreads();

    int g = bs[0];
    float acc = 0.f;
    for (int i = 0; i < cnt; ++i) {
        int bg = bs[i];
        if (bg != g) {
            atomicAdd(&sums[(size_t)g * HD + t], acc);
            acc = 0.f;
            g = bg;
        }
        acc += h[(size_t)(r0 + i) * HD + t];
    }
    atomicAdd(&sums[(size_t)g * HD + t], acc);
}

// ---------------- Mean-pool stage 2: mean + FC ----------------

__global__ __launch_bounds__(128) void k_fc(const float* __restrict__ sums,
                                            const int* __restrict__ batch,
                                            const float* __restrict__ Wfc,
                                            const float* __restrict__ bfc,
                                            float* __restrict__ out, int n) {
    int g = blockIdx.x;
    int t = threadIdx.x;   // 128 threads, one feature each
    __shared__ int slo, shi;
    if (t == 0) {
        int lo = 0, hi = n;
        while (lo < hi) { int m = (lo + hi) >> 1; if (batch[m] < g) lo = m + 1; else hi = m; }
        slo = lo;
        lo = 0; hi = n;
        while (lo < hi) { int m = (lo + hi) >> 1; if (batch[m] < g + 1) lo = m + 1; else hi = m; }
        shi = lo;
    }
    __syncthreads();
    float cnt = (float)(shi - slo);
    __shared__ float sp[HD];
    sp[t] = sums[(size_t)g * HD + t] / fmaxf(cnt, 1.f);
    __syncthreads();
    if (t < NL) {
        float o = bfc[t];
        for (int k = 0; k < HD; ++k) o = fmaf(sp[k], Wfc[k * NL + t], o);
        out[g * NL + t] = o;
    }
}

// ---------------- launch ----------------

extern "C" void kernel_launch(void* const* d_in, const int* in_sizes, int n_in,
                              void* d_out, int out_size, void* d_ws, size_t ws_size,
                              hipStream_t stream) {
    const float* x    = (const float*)d_in[0];
    const int*   ei   = (const int*)d_in[1];
    const int*   batch= (const int*)d_in[2];
    const float* W1   = (const float*)d_in[3];
    const float* b1   = (const float*)d_in[4];
    const float* W2   = (const float*)d_in[5];
    const float* b2   = (const float*)d_in[6];
    const float* Wfc  = (const float*)d_in[7];
    const float* bfc  = (const float*)d_in[8];
    float* out = (float*)d_out;

    int n = in_sizes[0] / HD;       // 50000
    int E = in_sizes[1] / 2;        // 800000
    int G = out_size / NL;          // 128
    const int* srcp = ei;
    const int* dstp = ei + E;

    char* ws = (char*)d_ws;
    auto align256 = [](size_t v) { return (v + 255) & ~(size_t)255; };
    size_t o = 0;
    int*   counts    = (int*)(ws + o); o = align256(o + (size_t)n * 4);
    int*   cursor    = (int*)(ws + o); o = align256(o + (size_t)n * 4);
    int*   row_start = (int*)(ws + o); o = align256(o + (size_t)(n + 1) * 4);
    float* dinv      = (float*)(ws + o); o = align256(o + (size_t)n * 4);
    int*   col       = (int*)(ws + o); o = align256(o + (size_t)E * 4);
    float* tmp       = (float*)(ws + o); o = align256(o + (size_t)n * HD * 4);
    float* hbuf      = (float*)(ws + o); o = align256(o + (size_t)n * HD * 4);
    float* sums      = (float*)(ws + o); o = align256(o + (size_t)G * HD * 4);

    hipMemsetAsync(counts, 0, (size_t)n * 4, stream);
    hipMemsetAsync(cursor, 0, (size_t)n * 4, stream);
    hipMemsetAsync(sums,   0, (size_t)G * HD * 4, stream);

    k_count<<<(E + 255) / 256, 256, 0, stream>>>(dstp, E, counts);
    k_dinv <<<(n + 255) / 256, 256, 0, stream>>>(counts, dinv, n);
    k_scan <<<1, 1024, 0, stream>>>(counts, row_start, n);
    k_fill <<<(E + 255) / 256, 256, 0, stream>>>(srcp, dstp, E, row_start, cursor, col);

    k_gemm128<<<(n + 63) / 64, 256, 0, stream>>>(x, W1, tmp, n);
    k_agg    <<<(n + 3) / 4, 256, 0, stream>>>(tmp, dinv, row_start, col, b1, hbuf, n);
    k_gemm128<<<(n + 63) / 64, 256, 0, stream>>>(hbuf, W2, tmp, n);
    k_agg    <<<(n + 3) / 4, 256, 0, stream>>>(tmp, dinv, row_start, col, b2, hbuf, n);

    k_pool_partial<<<(n + POOL_ROWS - 1) / POOL_ROWS, 128, 0, stream>>>(hbuf, batch, sums, n);
    k_fc<<<G, 128, 0, stream>>>(sums, batch, Wfc, bfc, out, n);
}

// Round 3
// 359.226 us; speedup vs baseline: 1.2693x; 1.1764x over previous
//
#include <hip/hip_runtime.h>
#include <hip/hip_bf16.h>

#define HD 128   // hidden/feature dim
#define NL 7     // label dim

// ---------------- CSR build ----------------

__global__ void k_count(const int* __restrict__ dst, int E, int* __restrict__ counts) {
    int i = blockIdx.x * blockDim.x + threadIdx.x;
    if (i < E) atomicAdd(&counts[dst[i]], 1);
}

__global__ void k_dinv(const int* __restrict__ counts, float* __restrict__ dinv, int n) {
    int v = blockIdx.x * blockDim.x + threadIdx.x;
    if (v < n) dinv[v] = 1.0f / sqrtf((float)(counts[v] + 1));  // +1 self loop, deg>=1
}

// ---- hierarchical prefix scan: local (256/block) -> block sums -> add ----

__global__ __launch_bounds__(256) void k_scan_local(const int* __restrict__ counts,
                                                    int* __restrict__ row_start,
                                                    int* __restrict__ bsum, int n) {
    __shared__ int s[256];
    int t = threadIdx.x;
    int i = blockIdx.x * 256 + t;
    int val = (i < n) ? counts[i] : 0;
    s[t] = val;
    __syncthreads();
    #pragma unroll
    for (int off = 1; off < 256; off <<= 1) {
        int v = (t >= off) ? s[t - off] : 0;
        __syncthreads();
        s[t] += v;
        __syncthreads();
    }
    if (i < n) row_start[i] = s[t] - val;     // local exclusive
    if (t == 255) bsum[blockIdx.x] = s[255];  // block total
}

__global__ __launch_bounds__(256) void k_scan_bsums(int* __restrict__ bsum,
                                                    int* __restrict__ row_start,
                                                    int nblk, int n) {
    __shared__ int s[256];
    int t = threadIdx.x;
    int val = (t < nblk) ? bsum[t] : 0;
    s[t] = val;
    __syncthreads();
    #pragma unroll
    for (int off = 1; off < 256; off <<= 1) {
        int v = (t >= off) ? s[t - off] : 0;
        __syncthreads();
        s[t] += v;
        __syncthreads();
    }
    if (t < nblk) bsum[t] = s[t] - val;       // exclusive block offsets
    if (t == 255) row_start[n] = s[255];      // grand total
}

__global__ __launch_bounds__(256) void k_scan_add(int* __restrict__ row_start,
                                                  const int* __restrict__ bsum, int n) {
    int i = blockIdx.x * 256 + threadIdx.x;
    if (i < n) row_start[i] += bsum[blockIdx.x];
}

__global__ void k_fill(const int* __restrict__ src, const int* __restrict__ dst, int E,
                       const int* __restrict__ row_start, int* __restrict__ cursor,
                       int* __restrict__ col) {
    int i = blockIdx.x * blockDim.x + threadIdx.x;
    if (i < E) {
        int d = dst[i];
        int pos = row_start[d] + atomicAdd(&cursor[d], 1);
        col[pos] = src[i];
    }
}

// ---------------- GEMM: Y[n,128] = X[n,128] @ W[128,128] ----------------
// 64-row tile in LDS, W rows streamed from global (64KB -> L1/L2 resident).
// 256 threads: 32 col-threads (float4) x 8 row-groups, each thread 8 rows x 4 cols.

__global__ __launch_bounds__(256) void k_gemm128(const float* __restrict__ X,
                                                 const float* __restrict__ W,
                                                 float* __restrict__ Y, int n) {
    __shared__ float xs[64][HD];
    int tid = threadIdx.x;
    int row0 = blockIdx.x * 64;

    // stage x tile: 8192 floats = 2048 float4, 8 per thread, coalesced
    #pragma unroll
    for (int j = 0; j < 8; ++j) {
        int f4 = tid + j * 256;        // 0..2047
        int r = f4 >> 5;               // 32 float4 per row
        int c = (f4 & 31) * 4;
        int gr = row0 + r;
        float4 v = make_float4(0.f, 0.f, 0.f, 0.f);
        if (gr < n) v = *(const float4*)&X[(size_t)gr * HD + c];
        *(float4*)&xs[r][c] = v;
    }
    __syncthreads();

    int cg = (tid & 31) * 4;       // this thread's 4 output cols
    int rg = (tid >> 5) * 8;       // this thread's 8 rows (tile-local)

    float4 acc[8];
    #pragma unroll
    for (int i = 0; i < 8; ++i) acc[i] = make_float4(0.f, 0.f, 0.f, 0.f);

    for (int k = 0; k < HD; k += 4) {
        float4 w0 = *(const float4*)&W[(size_t)(k + 0) * HD + cg];
        float4 w1 = *(const float4*)&W[(size_t)(k + 1) * HD + cg];
        float4 w2 = *(const float4*)&W[(size_t)(k + 2) * HD + cg];
        float4 w3 = *(const float4*)&W[(size_t)(k + 3) * HD + cg];
        #pragma unroll
        for (int i = 0; i < 8; ++i) {
            float4 xv = *(const float4*)&xs[rg + i][k];
            acc[i].x = fmaf(xv.x, w0.x, acc[i].x);
            acc[i].y = fmaf(xv.x, w0.y, acc[i].y);
            acc[i].z = fmaf(xv.x, w0.z, acc[i].z);
            acc[i].w = fmaf(xv.x, w0.w, acc[i].w);
            acc[i].x = fmaf(xv.y, w1.x, acc[i].x);
            acc[i].y = fmaf(xv.y, w1.y, acc[i].y);
            acc[i].z = fmaf(xv.y, w1.z, acc[i].z);
            acc[i].w = fmaf(xv.y, w1.w, acc[i].w);
            acc[i].x = fmaf(xv.z, w2.x, acc[i].x);
            acc[i].y = fmaf(xv.z, w2.y, acc[i].y);
            acc[i].z = fmaf(xv.z, w2.z, acc[i].z);
            acc[i].w = fmaf(xv.z, w2.w, acc[i].w);
            acc[i].x = fmaf(xv.w, w3.x, acc[i].x);
            acc[i].y = fmaf(xv.w, w3.y, acc[i].y);
            acc[i].z = fmaf(xv.w, w3.z, acc[i].z);
            acc[i].w = fmaf(xv.w, w3.w, acc[i].w);
        }
    }

    #pragma unroll
    for (int i = 0; i < 8; ++i) {
        int gr = row0 + rg + i;
        if (gr < n) *(float4*)&Y[(size_t)gr * HD + cg] = acc[i];
    }
}

// ---------------- Aggregation: out[v] = relu( sum_{s in N(v)} h[s]*dinv[s]*dinv[v]
//                                              + h[v]*dinv[v]^2 + bias ) ----------------
// One wave per node; each lane owns 2 features (float2). 4-edge unroll for MLP.

__global__ __launch_bounds__(256) void k_agg(const float* __restrict__ hin,
                                             const float* __restrict__ dinv,
                                             const int* __restrict__ row_start,
                                             const int* __restrict__ col,
                                             const float* __restrict__ bias,
                                             float* __restrict__ hout, int n) {
    int wave = threadIdx.x >> 6;
    int lane = threadIdx.x & 63;
    int v = blockIdx.x * 4 + wave;
    if (v >= n) return;

    float dv = dinv[v];
    int f = lane * 2;
    float2 acc = *(const float2*)(hin + (size_t)v * HD + f);
    float selfw = dv * dv;
    acc.x *= selfw; acc.y *= selfw;

    int e = row_start[v], e1 = row_start[v + 1];
    for (; e + 4 <= e1; e += 4) {
        int s0 = col[e], s1 = col[e + 1], s2 = col[e + 2], s3 = col[e + 3];
        float w0 = dinv[s0] * dv, w1 = dinv[s1] * dv, w2 = dinv[s2] * dv, w3 = dinv[s3] * dv;
        float2 a0 = *(const float2*)(hin + (size_t)s0 * HD + f);
        float2 a1 = *(const float2*)(hin + (size_t)s1 * HD + f);
        float2 a2 = *(const float2*)(hin + (size_t)s2 * HD + f);
        float2 a3 = *(const float2*)(hin + (size_t)s3 * HD + f);
        acc.x = fmaf(a0.x, w0, acc.x); acc.y = fmaf(a0.y, w0, acc.y);
        acc.x = fmaf(a1.x, w1, acc.x); acc.y = fmaf(a1.y, w1, acc.y);
        acc.x = fmaf(a2.x, w2, acc.x); acc.y = fmaf(a2.y, w2, acc.y);
        acc.x = fmaf(a3.x, w3, acc.x); acc.y = fmaf(a3.y, w3, acc.y);
    }
    for (; e < e1; ++e) {
        int s = col[e];
        float w = dinv[s] * dv;
        float2 a = *(const float2*)(hin + (size_t)s * HD + f);
        acc.x = fmaf(a.x, w, acc.x); acc.y = fmaf(a.y, w, acc.y);
    }

    float2 b = *(const float2*)(bias + f);
    float2 o;
    o.x = fmaxf(acc.x + b.x, 0.f);
    o.y = fmaxf(acc.y + b.y, 0.f);
    *(float2*)(hout + (size_t)v * HD + f) = o;
}

// ---------------- Mean-pool stage 1: per-chunk segmented partial sums ----------------

#define POOL_ROWS 256

__global__ __launch_bounds__(128) void k_pool_partial(const float* __restrict__ h,
                                                      const int* __restrict__ batch,
                                                      float* __restrict__ sums, int n) {
    __shared__ int bs[POOL_ROWS];
    int t = threadIdx.x;
    int r0 = blockIdx.x * POOL_ROWS;
    int r1 = min(r0 + POOL_ROWS, n);
    int cnt = r1 - r0;
    for (int i = t; i < cnt; i += 128) bs[i] = batch[r0 + i];
    __syncthreads();

    int g = bs[0];
    float acc = 0.f;
    for (int i = 0; i < cnt; ++i) {
        int bg = bs[i];
        if (bg != g) {
            atomicAdd(&sums[(size_t)g * HD + t], acc);
            acc = 0.f;
            g = bg;
        }
        acc += h[(size_t)(r0 + i) * HD + t];
    }
    atomicAdd(&sums[(size_t)g * HD + t], acc);
}

// ---------------- Mean-pool stage 2: mean + FC ----------------

__global__ __launch_bounds__(128) void k_fc(const float* __restrict__ sums,
                                            const int* __restrict__ batch,
                                            const float* __restrict__ Wfc,
                                            const float* __restrict__ bfc,
                                            float* __restrict__ out, int n) {
    int g = blockIdx.x;
    int t = threadIdx.x;   // 128 threads, one feature each
    __shared__ int slo, shi;
    if (t == 0) {
        int lo = 0, hi = n;
        while (lo < hi) { int m = (lo + hi) >> 1; if (batch[m] < g) lo = m + 1; else hi = m; }
        slo = lo;
        lo = 0; hi = n;
        while (lo < hi) { int m = (lo + hi) >> 1; if (batch[m] < g + 1) lo = m + 1; else hi = m; }
        shi = lo;
    }
    __syncthreads();
    float cnt = (float)(shi - slo);
    __shared__ float sp[HD];
    sp[t] = sums[(size_t)g * HD + t] / fmaxf(cnt, 1.f);
    __syncthreads();
    if (t < NL) {
        float o = bfc[t];
        for (int k = 0; k < HD; ++k) o = fmaf(sp[k], Wfc[k * NL + t], o);
        out[g * NL + t] = o;
    }
}

// ---------------- launch ----------------

extern "C" void kernel_launch(void* const* d_in, const int* in_sizes, int n_in,
                              void* d_out, int out_size, void* d_ws, size_t ws_size,
                              hipStream_t stream) {
    const float* x    = (const float*)d_in[0];
    const int*   ei   = (const int*)d_in[1];
    const int*   batch= (const int*)d_in[2];
    const float* W1   = (const float*)d_in[3];
    const float* b1   = (const float*)d_in[4];
    const float* W2   = (const float*)d_in[5];
    const float* b2   = (const float*)d_in[6];
    const float* Wfc  = (const float*)d_in[7];
    const float* bfc  = (const float*)d_in[8];
    float* out = (float*)d_out;

    int n = in_sizes[0] / HD;       // 50000
    int E = in_sizes[1] / 2;        // 800000
    int G = out_size / NL;          // 128
    const int* srcp = ei;
    const int* dstp = ei + E;

    int nblk = (n + 255) / 256;     // 196 (fits single-block level-2 scan, n<=65536)

    char* ws = (char*)d_ws;
    auto align256 = [](size_t v) { return (v + 255) & ~(size_t)255; };
    size_t o = 0;
    int*   counts    = (int*)(ws + o); o = align256(o + (size_t)n * 4);
    int*   cursor    = (int*)(ws + o); o = align256(o + (size_t)n * 4);
    int*   row_start = (int*)(ws + o); o = align256(o + (size_t)(n + 1) * 4);
    int*   bsum      = (int*)(ws + o); o = align256(o + (size_t)nblk * 4);
    float* dinv      = (float*)(ws + o); o = align256(o + (size_t)n * 4);
    int*   col       = (int*)(ws + o); o = align256(o + (size_t)E * 4);
    float* tmp       = (float*)(ws + o); o = align256(o + (size_t)n * HD * 4);
    float* hbuf      = (float*)(ws + o); o = align256(o + (size_t)n * HD * 4);
    float* sums      = (float*)(ws + o); o = align256(o + (size_t)G * HD * 4);

    hipMemsetAsync(counts, 0, (size_t)n * 4, stream);
    hipMemsetAsync(cursor, 0, (size_t)n * 4, stream);
    hipMemsetAsync(sums,   0, (size_t)G * HD * 4, stream);

    k_count<<<(E + 255) / 256, 256, 0, stream>>>(dstp, E, counts);
    k_dinv <<<nblk, 256, 0, stream>>>(counts, dinv, n);
    k_scan_local<<<nblk, 256, 0, stream>>>(counts, row_start, bsum, n);
    k_scan_bsums<<<1, 256, 0, stream>>>(bsum, row_start, nblk, n);
    k_scan_add  <<<nblk, 256, 0, stream>>>(row_start, bsum, n);
    k_fill<<<(E + 255) / 256, 256, 0, stream>>>(srcp, dstp, E, row_start, cursor, col);

    k_gemm128<<<(n + 63) / 64, 256, 0, stream>>>(x, W1, tmp, n);
    k_agg    <<<(n + 3) / 4, 256, 0, stream>>>(tmp, dinv, row_start, col, b1, hbuf, n);
    k_gemm128<<<(n + 63) / 64, 256, 0, stream>>>(hbuf, W2, tmp, n);
    k_agg    <<<(n + 3) / 4, 256, 0, stream>>>(tmp, dinv, row_start, col, b2, hbuf, n);

    k_pool_partial<<<(n + POOL_ROWS - 1) / POOL_ROWS, 128, 0, stream>>>(hbuf, batch, sums, n);
    k_fc<<<G, 128, 0, stream>>>(sums, batch, Wfc, bfc, out, n);
}

// Round 4
// 295.083 us; speedup vs baseline: 1.5452x; 1.2174x over previous
//
#include <hip/hip_runtime.h>
#include <hip/hip_bf16.h>

#define HD 128   // hidden/feature dim
#define NL 7     // label dim

// ---------------- CSR build ----------------

__global__ void k_count(const int* __restrict__ dst, int E, int* __restrict__ counts) {
    int i = blockIdx.x * blockDim.x + threadIdx.x;
    if (i < E) atomicAdd(&counts[dst[i]], 1);
}

__global__ void k_dinv(const int* __restrict__ counts, float* __restrict__ dinv, int n) {
    int v = blockIdx.x * blockDim.x + threadIdx.x;
    if (v < n) dinv[v] = 1.0f / sqrtf((float)(counts[v] + 1));  // +1 self loop, deg>=1
}

// ---- hierarchical prefix scan: local (256/block) -> block sums -> add ----

__global__ __launch_bounds__(256) void k_scan_local(const int* __restrict__ counts,
                                                    int* __restrict__ row_start,
                                                    int* __restrict__ bsum, int n) {
    __shared__ int s[256];
    int t = threadIdx.x;
    int i = blockIdx.x * 256 + t;
    int val = (i < n) ? counts[i] : 0;
    s[t] = val;
    __syncthreads();
    #pragma unroll
    for (int off = 1; off < 256; off <<= 1) {
        int v = (t >= off) ? s[t - off] : 0;
        __syncthreads();
        s[t] += v;
        __syncthreads();
    }
    if (i < n) row_start[i] = s[t] - val;     // local exclusive
    if (t == 255) bsum[blockIdx.x] = s[255];  // block total
}

__global__ __launch_bounds__(256) void k_scan_bsums(int* __restrict__ bsum,
                                                    int* __restrict__ row_start,
                                                    int nblk, int n) {
    __shared__ int s[256];
    int t = threadIdx.x;
    int val = (t < nblk) ? bsum[t] : 0;
    s[t] = val;
    __syncthreads();
    #pragma unroll
    for (int off = 1; off < 256; off <<= 1) {
        int v = (t >= off) ? s[t - off] : 0;
        __syncthreads();
        s[t] += v;
        __syncthreads();
    }
    if (t < nblk) bsum[t] = s[t] - val;       // exclusive block offsets
    if (t == 255) row_start[n] = s[255];      // grand total
}

__global__ __launch_bounds__(256) void k_scan_add(int* __restrict__ row_start,
                                                  const int* __restrict__ bsum, int n) {
    int i = blockIdx.x * 256 + threadIdx.x;
    if (i < n) row_start[i] += bsum[blockIdx.x];
}

__global__ void k_fill(const int* __restrict__ src, const int* __restrict__ dst, int E,
                       const int* __restrict__ row_start, int* __restrict__ cursor,
                       int* __restrict__ col) {
    int i = blockIdx.x * blockDim.x + threadIdx.x;
    if (i < E) {
        int d = dst[i];
        int pos = row_start[d] + atomicAdd(&cursor[d], 1);
        col[pos] = src[i];
    }
}

// ---------------- GEMM: Y[n,128] = X[n,128] @ W[128,128] ----------------
// 64-row tile in LDS, W rows streamed from global (64KB -> L1/L2 resident).
// 256 threads: 32 col-threads (float4) x 8 row-groups, each thread 8 rows x 4 cols.

__global__ __launch_bounds__(256) void k_gemm128(const float* __restrict__ X,
                                                 const float* __restrict__ W,
                                                 float* __restrict__ Y, int n) {
    __shared__ float xs[64][HD];
    int tid = threadIdx.x;
    int row0 = blockIdx.x * 64;

    // stage x tile: 8192 floats = 2048 float4, 8 per thread, coalesced
    #pragma unroll
    for (int j = 0; j < 8; ++j) {
        int f4 = tid + j * 256;        // 0..2047
        int r = f4 >> 5;               // 32 float4 per row
        int c = (f4 & 31) * 4;
        int gr = row0 + r;
        float4 v = make_float4(0.f, 0.f, 0.f, 0.f);
        if (gr < n) v = *(const float4*)&X[(size_t)gr * HD + c];
        *(float4*)&xs[r][c] = v;
    }
    __syncthreads();

    int cg = (tid & 31) * 4;       // this thread's 4 output cols
    int rg = (tid >> 5) * 8;       // this thread's 8 rows (tile-local)

    float4 acc[8];
    #pragma unroll
    for (int i = 0; i < 8; ++i) acc[i] = make_float4(0.f, 0.f, 0.f, 0.f);

    for (int k = 0; k < HD; k += 4) {
        float4 w0 = *(const float4*)&W[(size_t)(k + 0) * HD + cg];
        float4 w1 = *(const float4*)&W[(size_t)(k + 1) * HD + cg];
        float4 w2 = *(const float4*)&W[(size_t)(k + 2) * HD + cg];
        float4 w3 = *(const float4*)&W[(size_t)(k + 3) * HD + cg];
        #pragma unroll
        for (int i = 0; i < 8; ++i) {
            float4 xv = *(const float4*)&xs[rg + i][k];
            acc[i].x = fmaf(xv.x, w0.x, acc[i].x);
            acc[i].y = fmaf(xv.x, w0.y, acc[i].y);
            acc[i].z = fmaf(xv.x, w0.z, acc[i].z);
            acc[i].w = fmaf(xv.x, w0.w, acc[i].w);
            acc[i].x = fmaf(xv.y, w1.x, acc[i].x);
            acc[i].y = fmaf(xv.y, w1.y, acc[i].y);
            acc[i].z = fmaf(xv.y, w1.z, acc[i].z);
            acc[i].w = fmaf(xv.y, w1.w, acc[i].w);
            acc[i].x = fmaf(xv.z, w2.x, acc[i].x);
            acc[i].y = fmaf(xv.z, w2.y, acc[i].y);
            acc[i].z = fmaf(xv.z, w2.z, acc[i].z);
            acc[i].w = fmaf(xv.z, w2.w, acc[i].w);
            acc[i].x = fmaf(xv.w, w3.x, acc[i].x);
            acc[i].y = fmaf(xv.w, w3.y, acc[i].y);
            acc[i].z = fmaf(xv.w, w3.z, acc[i].z);
            acc[i].w = fmaf(xv.w, w3.w, acc[i].w);
        }
    }

    #pragma unroll
    for (int i = 0; i < 8; ++i) {
        int gr = row0 + rg + i;
        if (gr < n) *(float4*)&Y[(size_t)gr * HD + cg] = acc[i];
    }
}

// ---------------- Aggregation: out[v] = relu( sum_{s in N(v)} h[s]*dinv[s]*dinv[v]
//                                              + h[v]*dinv[v]^2 + bias ) ----------------
// One wave per node; each lane owns 2 features (float2). 4-edge unroll for MLP.

__global__ __launch_bounds__(256) void k_agg(const float* __restrict__ hin,
                                             const float* __restrict__ dinv,
                                             const int* __restrict__ row_start,
                                             const int* __restrict__ col,
                                             const float* __restrict__ bias,
                                             float* __restrict__ hout, int n) {
    int wave = threadIdx.x >> 6;
    int lane = threadIdx.x & 63;
    int v = blockIdx.x * 4 + wave;
    if (v >= n) return;

    float dv = dinv[v];
    int f = lane * 2;
    float2 acc = *(const float2*)(hin + (size_t)v * HD + f);
    float selfw = dv * dv;
    acc.x *= selfw; acc.y *= selfw;

    int e = row_start[v], e1 = row_start[v + 1];
    for (; e + 4 <= e1; e += 4) {
        int s0 = col[e], s1 = col[e + 1], s2 = col[e + 2], s3 = col[e + 3];
        float w0 = dinv[s0] * dv, w1 = dinv[s1] * dv, w2 = dinv[s2] * dv, w3 = dinv[s3] * dv;
        float2 a0 = *(const float2*)(hin + (size_t)s0 * HD + f);
        float2 a1 = *(const float2*)(hin + (size_t)s1 * HD + f);
        float2 a2 = *(const float2*)(hin + (size_t)s2 * HD + f);
        float2 a3 = *(const float2*)(hin + (size_t)s3 * HD + f);
        acc.x = fmaf(a0.x, w0, acc.x); acc.y = fmaf(a0.y, w0, acc.y);
        acc.x = fmaf(a1.x, w1, acc.x); acc.y = fmaf(a1.y, w1, acc.y);
        acc.x = fmaf(a2.x, w2, acc.x); acc.y = fmaf(a2.y, w2, acc.y);
        acc.x = fmaf(a3.x, w3, acc.x); acc.y = fmaf(a3.y, w3, acc.y);
    }
    for (; e < e1; ++e) {
        int s = col[e];
        float w = dinv[s] * dv;
        float2 a = *(const float2*)(hin + (size_t)s * HD + f);
        acc.x = fmaf(a.x, w, acc.x); acc.y = fmaf(a.y, w, acc.y);
    }

    float2 b = *(const float2*)(bias + f);
    float2 o;
    o.x = fmaxf(acc.x + b.x, 0.f);
    o.y = fmaxf(acc.y + b.y, 0.f);
    *(float2*)(hout + (size_t)v * HD + f) = o;
}

// ---------------- Mean-pool stage 1: per-chunk segmented partial sums ----------------
// 32 rows per block -> ~1563 blocks (6/CU) so the serial row loop is short and
// memory latency is hidden by TLP. Boundary flushes via float atomicAdd (rare).

#define POOL_ROWS 32

__global__ __launch_bounds__(128) void k_pool_partial(const float* __restrict__ h,
                                                      const int* __restrict__ batch,
                                                      float* __restrict__ sums, int n) {
    __shared__ int bs[POOL_ROWS];
    int t = threadIdx.x;
    int r0 = blockIdx.x * POOL_ROWS;
    int r1 = min(r0 + POOL_ROWS, n);
    int cnt = r1 - r0;
    if (t < cnt) bs[t] = batch[r0 + t];
    __syncthreads();

    int g = bs[0];
    float acc = 0.f;
    for (int i = 0; i < cnt; ++i) {
        int bg = bs[i];
        if (bg != g) {
            atomicAdd(&sums[(size_t)g * HD + t], acc);
            acc = 0.f;
            g = bg;
        }
        acc += h[(size_t)(r0 + i) * HD + t];
    }
    atomicAdd(&sums[(size_t)g * HD + t], acc);
}

// ---------------- Mean-pool stage 2: mean + FC ----------------

__global__ __launch_bounds__(128) void k_fc(const float* __restrict__ sums,
                                            const int* __restrict__ batch,
                                            const float* __restrict__ Wfc,
                                            const float* __restrict__ bfc,
                                            float* __restrict__ out, int n) {
    int g = blockIdx.x;
    int t = threadIdx.x;   // 128 threads, one feature each
    __shared__ int slo, shi;
    if (t == 0) {
        int lo = 0, hi = n;
        while (lo < hi) { int m = (lo + hi) >> 1; if (batch[m] < g) lo = m + 1; else hi = m; }
        slo = lo;
        lo = 0; hi = n;
        while (lo < hi) { int m = (lo + hi) >> 1; if (batch[m] < g + 1) lo = m + 1; else hi = m; }
        shi = lo;
    }
    __syncthreads();
    float cnt = (float)(shi - slo);
    __shared__ float sp[HD];
    sp[t] = sums[(size_t)g * HD + t] / fmaxf(cnt, 1.f);
    __syncthreads();
    if (t < NL) {
        float o = bfc[t];
        for (int k = 0; k < HD; ++k) o = fmaf(sp[k], Wfc[k * NL + t], o);
        out[g * NL + t] = o;
    }
}

// ---------------- launch ----------------

extern "C" void kernel_launch(void* const* d_in, const int* in_sizes, int n_in,
                              void* d_out, int out_size, void* d_ws, size_t ws_size,
                              hipStream_t stream) {
    const float* x    = (const float*)d_in[0];
    const int*   ei   = (const int*)d_in[1];
    const int*   batch= (const int*)d_in[2];
    const float* W1   = (const float*)d_in[3];
    const float* b1   = (const float*)d_in[4];
    const float* W2   = (const float*)d_in[5];
    const float* b2   = (const float*)d_in[6];
    const float* Wfc  = (const float*)d_in[7];
    const float* bfc  = (const float*)d_in[8];
    float* out = (float*)d_out;

    int n = in_sizes[0] / HD;       // 50000
    int E = in_sizes[1] / 2;        // 800000
    int G = out_size / NL;          // 128
    const int* srcp = ei;
    const int* dstp = ei + E;

    int nblk = (n + 255) / 256;     // 196 (fits single-block level-2 scan, n<=65536)

    char* ws = (char*)d_ws;
    auto align256 = [](size_t v) { return (v + 255) & ~(size_t)255; };
    size_t o = 0;
    int*   counts    = (int*)(ws + o); o = align256(o + (size_t)n * 4);
    int*   cursor    = (int*)(ws + o); o = align256(o + (size_t)n * 4);
    int*   row_start = (int*)(ws + o); o = align256(o + (size_t)(n + 1) * 4);
    int*   bsum      = (int*)(ws + o); o = align256(o + (size_t)nblk * 4);
    float* dinv      = (float*)(ws + o); o = align256(o + (size_t)n * 4);
    int*   col       = (int*)(ws + o); o = align256(o + (size_t)E * 4);
    float* tmp       = (float*)(ws + o); o = align256(o + (size_t)n * HD * 4);
    float* hbuf      = (float*)(ws + o); o = align256(o + (size_t)n * HD * 4);
    float* sums      = (float*)(ws + o); o = align256(o + (size_t)G * HD * 4);

    hipMemsetAsync(counts, 0, (size_t)n * 4, stream);
    hipMemsetAsync(cursor, 0, (size_t)n * 4, stream);
    hipMemsetAsync(sums,   0, (size_t)G * HD * 4, stream);

    k_count<<<(E + 255) / 256, 256, 0, stream>>>(dstp, E, counts);
    k_dinv <<<nblk, 256, 0, stream>>>(counts, dinv, n);
    k_scan_local<<<nblk, 256, 0, stream>>>(counts, row_start, bsum, n);
    k_scan_bsums<<<1, 256, 0, stream>>>(bsum, row_start, nblk, n);
    k_scan_add  <<<nblk, 256, 0, stream>>>(row_start, bsum, n);
    k_fill<<<(E + 255) / 256, 256, 0, stream>>>(srcp, dstp, E, row_start, cursor, col);

    k_gemm128<<<(n + 63) / 64, 256, 0, stream>>>(x, W1, tmp, n);
    k_agg    <<<(n + 3) / 4, 256, 0, stream>>>(tmp, dinv, row_start, col, b1, hbuf, n);
    k_gemm128<<<(n + 63) / 64, 256, 0, stream>>>(hbuf, W2, tmp, n);
    k_agg    <<<(n + 3) / 4, 256, 0, stream>>>(tmp, dinv, row_start, col, b2, hbuf, n);

    k_pool_partial<<<(n + POOL_ROWS - 1) / POOL_ROWS, 128, 0, stream>>>(hbuf, batch, sums, n);
    k_fc<<<G, 128, 0, stream>>>(sums, batch, Wfc, bfc, out, n);
}

// Round 5
// 262.855 us; speedup vs baseline: 1.7347x; 1.1226x over previous
//
#include <hip/hip_runtime.h>
#include <hip/hip_bf16.h>

#define HD 128   // hidden/feature dim
#define NL 7     // label dim

__device__ __forceinline__ unsigned short f2bf(float f) {
    __hip_bfloat16 b = __float2bfloat16(f);   // RNE
    return *reinterpret_cast<unsigned short*>(&b);
}
__device__ __forceinline__ float bf2f(unsigned short u) {
    unsigned int x = ((unsigned int)u) << 16;
    return __uint_as_float(x);
}

// ---------------- CSR build ----------------

__global__ void k_count(const int* __restrict__ dst, int E, int* __restrict__ counts) {
    int i = blockIdx.x * blockDim.x + threadIdx.x;
    if (i < E) atomicAdd(&counts[dst[i]], 1);
}

__global__ void k_dinv(const int* __restrict__ counts, float* __restrict__ dinv, int n) {
    int v = blockIdx.x * blockDim.x + threadIdx.x;
    if (v < n) dinv[v] = 1.0f / sqrtf((float)(counts[v] + 1));  // +1 self loop, deg>=1
}

// ---- hierarchical prefix scan: local (256/block) -> block sums -> add ----

__global__ __launch_bounds__(256) void k_scan_local(const int* __restrict__ counts,
                                                    int* __restrict__ row_start,
                                                    int* __restrict__ bsum, int n) {
    __shared__ int s[256];
    int t = threadIdx.x;
    int i = blockIdx.x * 256 + t;
    int val = (i < n) ? counts[i] : 0;
    s[t] = val;
    __syncthreads();
    #pragma unroll
    for (int off = 1; off < 256; off <<= 1) {
        int v = (t >= off) ? s[t - off] : 0;
        __syncthreads();
        s[t] += v;
        __syncthreads();
    }
    if (i < n) row_start[i] = s[t] - val;     // local exclusive
    if (t == 255) bsum[blockIdx.x] = s[255];  // block total
}

__global__ __launch_bounds__(256) void k_scan_bsums(int* __restrict__ bsum,
                                                    int* __restrict__ row_start,
                                                    int nblk, int n) {
    __shared__ int s[256];
    int t = threadIdx.x;
    int val = (t < nblk) ? bsum[t] : 0;
    s[t] = val;
    __syncthreads();
    #pragma unroll
    for (int off = 1; off < 256; off <<= 1) {
        int v = (t >= off) ? s[t - off] : 0;
        __syncthreads();
        s[t] += v;
        __syncthreads();
    }
    if (t < nblk) bsum[t] = s[t] - val;       // exclusive block offsets
    if (t == 255) row_start[n] = s[255];      // grand total
}

__global__ __launch_bounds__(256) void k_scan_add(int* __restrict__ row_start,
                                                  const int* __restrict__ bsum, int n) {
    int i = blockIdx.x * 256 + threadIdx.x;
    if (i < n) row_start[i] += bsum[blockIdx.x];
}

__global__ void k_fill(const int* __restrict__ src, const int* __restrict__ dst, int E,
                       const int* __restrict__ row_start, int* __restrict__ cursor,
                       int* __restrict__ col) {
    int i = blockIdx.x * blockDim.x + threadIdx.x;
    if (i < E) {
        int d = dst[i];
        int pos = row_start[d] + atomicAdd(&cursor[d], 1);
        col[pos] = src[i];
    }
}

// ---------------- GEMM: Y[n,128](bf16) = X[n,128](f32) @ W[128,128](f32) ----------------
// 64-row tile in LDS, W streamed (64KB, L2-resident). bf16 epilogue halves write
// traffic and shrinks the downstream gather's working set to 12.8MB.

__global__ __launch_bounds__(256) void k_gemm128(const float* __restrict__ X,
                                                 const float* __restrict__ W,
                                                 unsigned short* __restrict__ Y, int n) {
    __shared__ float xs[64][HD];
    int tid = threadIdx.x;
    int row0 = blockIdx.x * 64;

    #pragma unroll
    for (int j = 0; j < 8; ++j) {
        int f4 = tid + j * 256;        // 0..2047
        int r = f4 >> 5;               // 32 float4 per row
        int c = (f4 & 31) * 4;
        int gr = row0 + r;
        float4 v = make_float4(0.f, 0.f, 0.f, 0.f);
        if (gr < n) v = *(const float4*)&X[(size_t)gr * HD + c];
        *(float4*)&xs[r][c] = v;
    }
    __syncthreads();

    int cg = (tid & 31) * 4;       // this thread's 4 output cols
    int rg = (tid >> 5) * 8;       // this thread's 8 rows (tile-local)

    float4 acc[8];
    #pragma unroll
    for (int i = 0; i < 8; ++i) acc[i] = make_float4(0.f, 0.f, 0.f, 0.f);

    for (int k = 0; k < HD; k += 4) {
        float4 w0 = *(const float4*)&W[(size_t)(k + 0) * HD + cg];
        float4 w1 = *(const float4*)&W[(size_t)(k + 1) * HD + cg];
        float4 w2 = *(const float4*)&W[(size_t)(k + 2) * HD + cg];
        float4 w3 = *(const float4*)&W[(size_t)(k + 3) * HD + cg];
        #pragma unroll
        for (int i = 0; i < 8; ++i) {
            float4 xv = *(const float4*)&xs[rg + i][k];
            acc[i].x = fmaf(xv.x, w0.x, acc[i].x);
            acc[i].y = fmaf(xv.x, w0.y, acc[i].y);
            acc[i].z = fmaf(xv.x, w0.z, acc[i].z);
            acc[i].w = fmaf(xv.x, w0.w, acc[i].w);
            acc[i].x = fmaf(xv.y, w1.x, acc[i].x);
            acc[i].y = fmaf(xv.y, w1.y, acc[i].y);
            acc[i].z = fmaf(xv.y, w1.z, acc[i].z);
            acc[i].w = fmaf(xv.y, w1.w, acc[i].w);
            acc[i].x = fmaf(xv.z, w2.x, acc[i].x);
            acc[i].y = fmaf(xv.z, w2.y, acc[i].y);
            acc[i].z = fmaf(xv.z, w2.z, acc[i].z);
            acc[i].w = fmaf(xv.z, w2.w, acc[i].w);
            acc[i].x = fmaf(xv.w, w3.x, acc[i].x);
            acc[i].y = fmaf(xv.w, w3.y, acc[i].y);
            acc[i].z = fmaf(xv.w, w3.z, acc[i].z);
            acc[i].w = fmaf(xv.w, w3.w, acc[i].w);
        }
    }

    #pragma unroll
    for (int i = 0; i < 8; ++i) {
        int gr = row0 + rg + i;
        if (gr < n) {
            ushort4 o;
            o.x = f2bf(acc[i].x);
            o.y = f2bf(acc[i].y);
            o.z = f2bf(acc[i].z);
            o.w = f2bf(acc[i].w);
            *(ushort4*)&Y[(size_t)gr * HD + cg] = o;
        }
    }
}

// ---------------- Aggregation (bf16 gather, f32 accumulate) ----------------
// out[v] = relu( sum_{s in N(v)} h[s]*dinv[s]*dinv[v] + h[v]*dinv[v]^2 + bias )
// One wave per node; lane owns 2 features (ushort2 = 4B/lane -> 256B/row/wave).

__global__ __launch_bounds__(256) void k_agg(const unsigned short* __restrict__ hin,
                                             const float* __restrict__ dinv,
                                             const int* __restrict__ row_start,
                                             const int* __restrict__ col,
                                             const float* __restrict__ bias,
                                             float* __restrict__ hout, int n) {
    int wave = threadIdx.x >> 6;
    int lane = threadIdx.x & 63;
    int v = blockIdx.x * 4 + wave;
    if (v >= n) return;

    float dv = dinv[v];
    int f = lane * 2;
    ushort2 sv = *(const ushort2*)(hin + (size_t)v * HD + f);
    float selfw = dv * dv;
    float accx = bf2f(sv.x) * selfw;
    float accy = bf2f(sv.y) * selfw;

    int e = row_start[v], e1 = row_start[v + 1];
    for (; e + 8 <= e1; e += 8) {
        int s0 = col[e], s1 = col[e+1], s2 = col[e+2], s3 = col[e+3];
        int s4 = col[e+4], s5 = col[e+5], s6 = col[e+6], s7 = col[e+7];
        float w0 = dinv[s0]*dv, w1 = dinv[s1]*dv, w2 = dinv[s2]*dv, w3 = dinv[s3]*dv;
        float w4 = dinv[s4]*dv, w5 = dinv[s5]*dv, w6 = dinv[s6]*dv, w7 = dinv[s7]*dv;
        ushort2 a0 = *(const ushort2*)(hin + (size_t)s0 * HD + f);
        ushort2 a1 = *(const ushort2*)(hin + (size_t)s1 * HD + f);
        ushort2 a2 = *(const ushort2*)(hin + (size_t)s2 * HD + f);
        ushort2 a3 = *(const ushort2*)(hin + (size_t)s3 * HD + f);
        ushort2 a4 = *(const ushort2*)(hin + (size_t)s4 * HD + f);
        ushort2 a5 = *(const ushort2*)(hin + (size_t)s5 * HD + f);
        ushort2 a6 = *(const ushort2*)(hin + (size_t)s6 * HD + f);
        ushort2 a7 = *(const ushort2*)(hin + (size_t)s7 * HD + f);
        accx = fmaf(bf2f(a0.x), w0, accx); accy = fmaf(bf2f(a0.y), w0, accy);
        accx = fmaf(bf2f(a1.x), w1, accx); accy = fmaf(bf2f(a1.y), w1, accy);
        accx = fmaf(bf2f(a2.x), w2, accx); accy = fmaf(bf2f(a2.y), w2, accy);
        accx = fmaf(bf2f(a3.x), w3, accx); accy = fmaf(bf2f(a3.y), w3, accy);
        accx = fmaf(bf2f(a4.x), w4, accx); accy = fmaf(bf2f(a4.y), w4, accy);
        accx = fmaf(bf2f(a5.x), w5, accx); accy = fmaf(bf2f(a5.y), w5, accy);
        accx = fmaf(bf2f(a6.x), w6, accx); accy = fmaf(bf2f(a6.y), w6, accy);
        accx = fmaf(bf2f(a7.x), w7, accx); accy = fmaf(bf2f(a7.y), w7, accy);
    }
    for (; e < e1; ++e) {
        int s = col[e];
        float w = dinv[s] * dv;
        ushort2 a = *(const ushort2*)(hin + (size_t)s * HD + f);
        accx = fmaf(bf2f(a.x), w, accx); accy = fmaf(bf2f(a.y), w, accy);
    }

    float2 b = *(const float2*)(bias + f);
    float2 o;
    o.x = fmaxf(accx + b.x, 0.f);
    o.y = fmaxf(accy + b.y, 0.f);
    *(float2*)(hout + (size_t)v * HD + f) = o;
}

// ---------------- Mean-pool stage 1: per-chunk segmented partial sums ----------------
// 32 rows per block -> ~1563 blocks (6/CU): short serial chain, latency hidden by TLP.

#define POOL_ROWS 32

__global__ __launch_bounds__(128) void k_pool_partial(const float* __restrict__ h,
                                                      const int* __restrict__ batch,
                                                      float* __restrict__ sums, int n) {
    __shared__ int bs[POOL_ROWS];
    int t = threadIdx.x;
    int r0 = blockIdx.x * POOL_ROWS;
    int r1 = min(r0 + POOL_ROWS, n);
    int cnt = r1 - r0;
    if (t < cnt) bs[t] = batch[r0 + t];
    __syncthreads();

    int g = bs[0];
    float acc = 0.f;
    for (int i = 0; i < cnt; ++i) {
        int bg = bs[i];
        if (bg != g) {
            atomicAdd(&sums[(size_t)g * HD + t], acc);
            acc = 0.f;
            g = bg;
        }
        acc += h[(size_t)(r0 + i) * HD + t];
    }
    atomicAdd(&sums[(size_t)g * HD + t], acc);
}

// ---------------- Mean-pool stage 2: mean + FC ----------------

__global__ __launch_bounds__(128) void k_fc(const float* __restrict__ sums,
                                            const int* __restrict__ batch,
                                            const float* __restrict__ Wfc,
                                            const float* __restrict__ bfc,
                                            float* __restrict__ out, int n) {
    int g = blockIdx.x;
    int t = threadIdx.x;   // 128 threads, one feature each
    __shared__ int slo, shi;
    if (t == 0) {
        int lo = 0, hi = n;
        while (lo < hi) { int m = (lo + hi) >> 1; if (batch[m] < g) lo = m + 1; else hi = m; }
        slo = lo;
        lo = 0; hi = n;
        while (lo < hi) { int m = (lo + hi) >> 1; if (batch[m] < g + 1) lo = m + 1; else hi = m; }
        shi = lo;
    }
    __syncthreads();
    float cnt = (float)(shi - slo);
    __shared__ float sp[HD];
    sp[t] = sums[(size_t)g * HD + t] / fmaxf(cnt, 1.f);
    __syncthreads();
    if (t < NL) {
        float o = bfc[t];
        for (int k = 0; k < HD; ++k) o = fmaf(sp[k], Wfc[k * NL + t], o);
        out[g * NL + t] = o;
    }
}

// ---------------- launch ----------------

extern "C" void kernel_launch(void* const* d_in, const int* in_sizes, int n_in,
                              void* d_out, int out_size, void* d_ws, size_t ws_size,
                              hipStream_t stream) {
    const float* x    = (const float*)d_in[0];
    const int*   ei   = (const int*)d_in[1];
    const int*   batch= (const int*)d_in[2];
    const float* W1   = (const float*)d_in[3];
    const float* b1   = (const float*)d_in[4];
    const float* W2   = (const float*)d_in[5];
    const float* b2   = (const float*)d_in[6];
    const float* Wfc  = (const float*)d_in[7];
    const float* bfc  = (const float*)d_in[8];
    float* out = (float*)d_out;

    int n = in_sizes[0] / HD;       // 50000
    int E = in_sizes[1] / 2;        // 800000
    int G = out_size / NL;          // 128
    const int* srcp = ei;
    const int* dstp = ei + E;

    int nblk = (n + 255) / 256;     // 196 (fits single-block level-2 scan, n<=65536)

    char* ws = (char*)d_ws;
    auto align256 = [](size_t v) { return (v + 255) & ~(size_t)255; };
    size_t o = 0;
    int*   counts    = (int*)(ws + o); o = align256(o + (size_t)n * 4);
    int*   cursor    = (int*)(ws + o); o = align256(o + (size_t)n * 4);
    int*   row_start = (int*)(ws + o); o = align256(o + (size_t)(n + 1) * 4);
    int*   bsum      = (int*)(ws + o); o = align256(o + (size_t)nblk * 4);
    float* dinv      = (float*)(ws + o); o = align256(o + (size_t)n * 4);
    int*   col       = (int*)(ws + o); o = align256(o + (size_t)E * 4);
    unsigned short* tmp = (unsigned short*)(ws + o); o = align256(o + (size_t)n * HD * 2);
    float* hbuf      = (float*)(ws + o); o = align256(o + (size_t)n * HD * 4);
    float* sums      = (float*)(ws + o); o = align256(o + (size_t)G * HD * 4);

    hipMemsetAsync(counts, 0, (size_t)n * 4, stream);
    hipMemsetAsync(cursor, 0, (size_t)n * 4, stream);
    hipMemsetAsync(sums,   0, (size_t)G * HD * 4, stream);

    k_count<<<(E + 255) / 256, 256, 0, stream>>>(dstp, E, counts);
    k_dinv <<<nblk, 256, 0, stream>>>(counts, dinv, n);
    k_scan_local<<<nblk, 256, 0, stream>>>(counts, row_start, bsum, n);
    k_scan_bsums<<<1, 256, 0, stream>>>(bsum, row_start, nblk, n);
    k_scan_add  <<<nblk, 256, 0, stream>>>(row_start, bsum, n);
    k_fill<<<(E + 255) / 256, 256, 0, stream>>>(srcp, dstp, E, row_start, cursor, col);

    k_gemm128<<<(n + 63) / 64, 256, 0, stream>>>(x, W1, tmp, n);
    k_agg    <<<(n + 3) / 4, 256, 0, stream>>>(tmp, dinv, row_start, col, b1, hbuf, n);
    k_gemm128<<<(n + 63) / 64, 256, 0, stream>>>(hbuf, W2, tmp, n);
    k_agg    <<<(n + 3) / 4, 256, 0, stream>>>(tmp, dinv, row_start, col, b2, hbuf, n);

    k_pool_partial<<<(n + POOL_ROWS - 1) / POOL_ROWS, 128, 0, stream>>>(hbuf, batch, sums, n);
    k_fc<<<G, 128, 0, stream>>>(sums, batch, Wfc, bfc, out, n);
}

// Round 6
// 196.186 us; speedup vs baseline: 2.3242x; 1.3398x over previous
//
#include <hip/hip_runtime.h>
#include <hip/hip_bf16.h>

#define HD 128   // hidden/feature dim
#define NL 7     // label dim
#define BCAP 6144  // per-bucket stage capacity (avg 4082 for E=800K/196 buckets; +50% headroom)

__device__ __forceinline__ unsigned short f2bf(float f) {
    __hip_bfloat16 b = __float2bfloat16(f);   // RNE
    return *reinterpret_cast<unsigned short*>(&b);
}
__device__ __forceinline__ float bf2f(unsigned short u) {
    unsigned int x = ((unsigned int)u) << 16;
    return __uint_as_float(x);
}

// ---------------- CSR build via bucketed counting sort ----------------
// Bucket b = dst >> 8 covers 256 consecutive dst nodes. Phase 1 partitions the
// edge list into per-bucket regions with block-local dense writes (one global
// atomic per block x bucket). Phase 2: one block per bucket builds the local
// CSR (row_start, dinv, col) entirely in LDS, dense global writes.

__global__ __launch_bounds__(256) void k_bucket(const int* __restrict__ src,
                                                const int* __restrict__ dst, int E,
                                                int* __restrict__ gbcur,
                                                int* __restrict__ stage, int nb) {
    __shared__ int lh[256];
    __shared__ int gb[256];
    int t = threadIdx.x;
    if (t < nb) lh[t] = 0;
    __syncthreads();

    int e0 = blockIdx.x * 4096;
    int bk[16]; int lr[16]; int rec[16];
    #pragma unroll
    for (int j = 0; j < 16; ++j) {
        int e = e0 + j * 256 + t;
        if (e < E) {
            int d = dst[e];
            int s = src[e];
            bk[j]  = d >> 8;
            rec[j] = ((d & 255) << 16) | s;       // src < 65536
            lr[j]  = atomicAdd(&lh[bk[j]], 1);    // local rank
        } else {
            bk[j] = -1; lr[j] = 0; rec[j] = 0;
        }
    }
    __syncthreads();
    if (t < nb) gb[t] = atomicAdd(&gbcur[t], lh[t]);   // reserve run per bucket
    __syncthreads();
    #pragma unroll
    for (int j = 0; j < 16; ++j) {
        if (bk[j] >= 0) {
            int p = gb[bk[j]] + lr[j];
            if (p < BCAP) stage[bk[j] * BCAP + p] = rec[j];
        }
    }
}

__global__ __launch_bounds__(256) void k_bscan(const int* __restrict__ gbcnt,
                                               int* __restrict__ bbase, int nb,
                                               int* __restrict__ row_start, int n) {
    __shared__ int s[256];
    int t = threadIdx.x;
    int val = (t < nb) ? gbcnt[t] : 0;
    s[t] = val;
    __syncthreads();
    #pragma unroll
    for (int off = 1; off < 256; off <<= 1) {
        int v = (t >= off) ? s[t - off] : 0;
        __syncthreads();
        s[t] += v;
        __syncthreads();
    }
    if (t < nb) bbase[t] = s[t] - val;
    if (t == 255) { bbase[nb] = s[255]; row_start[n] = s[255]; }
}

__global__ __launch_bounds__(256) void k_build(const int* __restrict__ stage,
                                               const int* __restrict__ gbcnt,
                                               const int* __restrict__ bbase,
                                               int* __restrict__ col,
                                               int* __restrict__ row_start,
                                               float* __restrict__ dinv, int n) {
    __shared__ int rec_s[BCAP];
    __shared__ unsigned short rank_s[BCAP];
    __shared__ int hist[256];
    __shared__ int scan_s[256];
    int b = blockIdx.x, t = threadIdx.x;
    int cnt  = min(gbcnt[b], BCAP);
    int base = bbase[b];
    int node0 = b << 8;

    hist[t] = 0;
    __syncthreads();
    for (int e = t; e < cnt; e += 256) {
        int r = stage[b * BCAP + e];
        rec_s[e] = r;
        rank_s[e] = (unsigned short)atomicAdd(&hist[r >> 16], 1);
    }
    __syncthreads();

    int deg = hist[t];
    int node = node0 + t;
    if (node < n) dinv[node] = 1.0f / sqrtf((float)(deg + 1));  // +1 self loop

    scan_s[t] = deg;
    __syncthreads();
    #pragma unroll
    for (int off = 1; off < 256; off <<= 1) {
        int v = (t >= off) ? scan_s[t - off] : 0;
        __syncthreads();
        scan_s[t] += v;
        __syncthreads();
    }
    int lrs = scan_s[t] - deg;      // local exclusive prefix
    hist[t] = lrs;                  // reuse hist as lrs table
    if (node < n) row_start[node] = base + lrs;
    __syncthreads();

    for (int e = t; e < cnt; e += 256) {
        int r = rec_s[e];
        col[base + hist[r >> 16] + rank_s[e]] = r & 0xFFFF;
    }
}

// ---------------- GEMM: Y[n,128](bf16) = X[n,128](f32) @ W[128,128](f32) ----------------

__global__ __launch_bounds__(256) void k_gemm128(const float* __restrict__ X,
                                                 const float* __restrict__ W,
                                                 unsigned short* __restrict__ Y, int n) {
    __shared__ float xs[64][HD];
    int tid = threadIdx.x;
    int row0 = blockIdx.x * 64;

    #pragma unroll
    for (int j = 0; j < 8; ++j) {
        int f4 = tid + j * 256;        // 0..2047
        int r = f4 >> 5;               // 32 float4 per row
        int c = (f4 & 31) * 4;
        int gr = row0 + r;
        float4 v = make_float4(0.f, 0.f, 0.f, 0.f);
        if (gr < n) v = *(const float4*)&X[(size_t)gr * HD + c];
        *(float4*)&xs[r][c] = v;
    }
    __syncthreads();

    int cg = (tid & 31) * 4;
    int rg = (tid >> 5) * 8;

    float4 acc[8];
    #pragma unroll
    for (int i = 0; i < 8; ++i) acc[i] = make_float4(0.f, 0.f, 0.f, 0.f);

    for (int k = 0; k < HD; k += 4) {
        float4 w0 = *(const float4*)&W[(size_t)(k + 0) * HD + cg];
        float4 w1 = *(const float4*)&W[(size_t)(k + 1) * HD + cg];
        float4 w2 = *(const float4*)&W[(size_t)(k + 2) * HD + cg];
        float4 w3 = *(const float4*)&W[(size_t)(k + 3) * HD + cg];
        #pragma unroll
        for (int i = 0; i < 8; ++i) {
            float4 xv = *(const float4*)&xs[rg + i][k];
            acc[i].x = fmaf(xv.x, w0.x, acc[i].x);
            acc[i].y = fmaf(xv.x, w0.y, acc[i].y);
            acc[i].z = fmaf(xv.x, w0.z, acc[i].z);
            acc[i].w = fmaf(xv.x, w0.w, acc[i].w);
            acc[i].x = fmaf(xv.y, w1.x, acc[i].x);
            acc[i].y = fmaf(xv.y, w1.y, acc[i].y);
            acc[i].z = fmaf(xv.y, w1.z, acc[i].z);
            acc[i].w = fmaf(xv.y, w1.w, acc[i].w);
            acc[i].x = fmaf(xv.z, w2.x, acc[i].x);
            acc[i].y = fmaf(xv.z, w2.y, acc[i].y);
            acc[i].z = fmaf(xv.z, w2.z, acc[i].z);
            acc[i].w = fmaf(xv.z, w2.w, acc[i].w);
            acc[i].x = fmaf(xv.w, w3.x, acc[i].x);
            acc[i].y = fmaf(xv.w, w3.y, acc[i].y);
            acc[i].z = fmaf(xv.w, w3.z, acc[i].z);
            acc[i].w = fmaf(xv.w, w3.w, acc[i].w);
        }
    }

    #pragma unroll
    for (int i = 0; i < 8; ++i) {
        int gr = row0 + rg + i;
        if (gr < n) {
            ushort4 o;
            o.x = f2bf(acc[i].x);
            o.y = f2bf(acc[i].y);
            o.z = f2bf(acc[i].z);
            o.w = f2bf(acc[i].w);
            *(ushort4*)&Y[(size_t)gr * HD + cg] = o;
        }
    }
}

// ---------------- Aggregation (bf16 gather, f32 accumulate) ----------------

__global__ __launch_bounds__(256) void k_agg(const unsigned short* __restrict__ hin,
                                             const float* __restrict__ dinv,
                                             const int* __restrict__ row_start,
                                             const int* __restrict__ col,
                                             const float* __restrict__ bias,
                                             float* __restrict__ hout, int n) {
    int wave = threadIdx.x >> 6;
    int lane = threadIdx.x & 63;
    int v = blockIdx.x * 4 + wave;
    if (v >= n) return;

    float dv = dinv[v];
    int f = lane * 2;
    ushort2 sv = *(const ushort2*)(hin + (size_t)v * HD + f);
    float selfw = dv * dv;
    float accx = bf2f(sv.x) * selfw;
    float accy = bf2f(sv.y) * selfw;

    int e = row_start[v], e1 = row_start[v + 1];
    for (; e + 8 <= e1; e += 8) {
        int s0 = col[e], s1 = col[e+1], s2 = col[e+2], s3 = col[e+3];
        int s4 = col[e+4], s5 = col[e+5], s6 = col[e+6], s7 = col[e+7];
        float w0 = dinv[s0]*dv, w1 = dinv[s1]*dv, w2 = dinv[s2]*dv, w3 = dinv[s3]*dv;
        float w4 = dinv[s4]*dv, w5 = dinv[s5]*dv, w6 = dinv[s6]*dv, w7 = dinv[s7]*dv;
        ushort2 a0 = *(const ushort2*)(hin + (size_t)s0 * HD + f);
        ushort2 a1 = *(const ushort2*)(hin + (size_t)s1 * HD + f);
        ushort2 a2 = *(const ushort2*)(hin + (size_t)s2 * HD + f);
        ushort2 a3 = *(const ushort2*)(hin + (size_t)s3 * HD + f);
        ushort2 a4 = *(const ushort2*)(hin + (size_t)s4 * HD + f);
        ushort2 a5 = *(const ushort2*)(hin + (size_t)s5 * HD + f);
        ushort2 a6 = *(const ushort2*)(hin + (size_t)s6 * HD + f);
        ushort2 a7 = *(const ushort2*)(hin + (size_t)s7 * HD + f);
        accx = fmaf(bf2f(a0.x), w0, accx); accy = fmaf(bf2f(a0.y), w0, accy);
        accx = fmaf(bf2f(a1.x), w1, accx); accy = fmaf(bf2f(a1.y), w1, accy);
        accx = fmaf(bf2f(a2.x), w2, accx); accy = fmaf(bf2f(a2.y), w2, accy);
        accx = fmaf(bf2f(a3.x), w3, accx); accy = fmaf(bf2f(a3.y), w3, accy);
        accx = fmaf(bf2f(a4.x), w4, accx); accy = fmaf(bf2f(a4.y), w4, accy);
        accx = fmaf(bf2f(a5.x), w5, accx); accy = fmaf(bf2f(a5.y), w5, accy);
        accx = fmaf(bf2f(a6.x), w6, accx); accy = fmaf(bf2f(a6.y), w6, accy);
        accx = fmaf(bf2f(a7.x), w7, accx); accy = fmaf(bf2f(a7.y), w7, accy);
    }
    for (; e < e1; ++e) {
        int s = col[e];
        float w = dinv[s] * dv;
        ushort2 a = *(const ushort2*)(hin + (size_t)s * HD + f);
        accx = fmaf(bf2f(a.x), w, accx); accy = fmaf(bf2f(a.y), w, accy);
    }

    float2 b = *(const float2*)(bias + f);
    float2 o;
    o.x = fmaxf(accx + b.x, 0.f);
    o.y = fmaxf(accy + b.y, 0.f);
    *(float2*)(hout + (size_t)v * HD + f) = o;
}

// ---------------- Mean-pool stage 1: per-chunk segmented partial sums ----------------

#define POOL_ROWS 32

__global__ __launch_bounds__(128) void k_pool_partial(const float* __restrict__ h,
                                                      const int* __restrict__ batch,
                                                      float* __restrict__ sums, int n) {
    __shared__ int bs[POOL_ROWS];
    int t = threadIdx.x;
    int r0 = blockIdx.x * POOL_ROWS;
    int r1 = min(r0 + POOL_ROWS, n);
    int cnt = r1 - r0;
    if (t < cnt) bs[t] = batch[r0 + t];
    __syncthreads();

    int g = bs[0];
    float acc = 0.f;
    for (int i = 0; i < cnt; ++i) {
        int bg = bs[i];
        if (bg != g) {
            atomicAdd(&sums[(size_t)g * HD + t], acc);
            acc = 0.f;
            g = bg;
        }
        acc += h[(size_t)(r0 + i) * HD + t];
    }
    atomicAdd(&sums[(size_t)g * HD + t], acc);
}

// ---------------- Mean-pool stage 2: mean + FC ----------------

__global__ __launch_bounds__(128) void k_fc(const float* __restrict__ sums,
                                            const int* __restrict__ batch,
                                            const float* __restrict__ Wfc,
                                            const float* __restrict__ bfc,
                                            float* __restrict__ out, int n) {
    int g = blockIdx.x;
    int t = threadIdx.x;
    __shared__ int slo, shi;
    if (t == 0) {
        int lo = 0, hi = n;
        while (lo < hi) { int m = (lo + hi) >> 1; if (batch[m] < g) lo = m + 1; else hi = m; }
        slo = lo;
        lo = 0; hi = n;
        while (lo < hi) { int m = (lo + hi) >> 1; if (batch[m] < g + 1) lo = m + 1; else hi = m; }
        shi = lo;
    }
    __syncthreads();
    float cnt = (float)(shi - slo);
    __shared__ float sp[HD];
    sp[t] = sums[(size_t)g * HD + t] / fmaxf(cnt, 1.f);
    __syncthreads();
    if (t < NL) {
        float o = bfc[t];
        for (int k = 0; k < HD; ++k) o = fmaf(sp[k], Wfc[k * NL + t], o);
        out[g * NL + t] = o;
    }
}

// ---------------- launch ----------------

extern "C" void kernel_launch(void* const* d_in, const int* in_sizes, int n_in,
                              void* d_out, int out_size, void* d_ws, size_t ws_size,
                              hipStream_t stream) {
    const float* x    = (const float*)d_in[0];
    const int*   ei   = (const int*)d_in[1];
    const int*   batch= (const int*)d_in[2];
    const float* W1   = (const float*)d_in[3];
    const float* b1   = (const float*)d_in[4];
    const float* W2   = (const float*)d_in[5];
    const float* b2   = (const float*)d_in[6];
    const float* Wfc  = (const float*)d_in[7];
    const float* bfc  = (const float*)d_in[8];
    float* out = (float*)d_out;

    int n = in_sizes[0] / HD;       // 50000
    int E = in_sizes[1] / 2;        // 800000
    int G = out_size / NL;          // 128
    const int* srcp = ei;
    const int* dstp = ei + E;

    int nb = (n + 255) >> 8;        // 196 buckets of 256 dst nodes

    char* ws = (char*)d_ws;
    auto align256 = [](size_t v) { return (v + 255) & ~(size_t)255; };
    size_t o = 0;
    int*   row_start = (int*)(ws + o); o = align256(o + (size_t)(n + 1) * 4);
    int*   bbase     = (int*)(ws + o); o = align256(o + (size_t)(nb + 1) * 4);
    int*   gbcur     = (int*)(ws + o); o = align256(o + (size_t)nb * 4);
    float* dinv      = (float*)(ws + o); o = align256(o + (size_t)n * 4);
    int*   col       = (int*)(ws + o); o = align256(o + (size_t)E * 4);
    unsigned short* tmp = (unsigned short*)(ws + o); o = align256(o + (size_t)n * HD * 2);
    float* hbuf      = (float*)(ws + o); o = align256(o + (size_t)n * HD * 4);
    float* sums      = (float*)(ws + o); o = align256(o + (size_t)G * HD * 4);

    // stage aliases hbuf: consumed by k_build before hbuf's first write (k_agg #1)
    int* stage = (int*)hbuf;        // needs nb*BCAP*4 = 4.8MB <= 25.6MB

    hipMemsetAsync(gbcur, 0, (size_t)nb * 4, stream);
    hipMemsetAsync(sums,  0, (size_t)G * HD * 4, stream);

    int nblkC = (E + 4095) / 4096;  // 196
    k_bucket<<<nblkC, 256, 0, stream>>>(srcp, dstp, E, gbcur, stage, nb);
    k_bscan <<<1, 256, 0, stream>>>(gbcur, bbase, nb, row_start, n);
    k_build <<<nb, 256, 0, stream>>>(stage, gbcur, bbase, col, row_start, dinv, n);

    k_gemm128<<<(n + 63) / 64, 256, 0, stream>>>(x, W1, tmp, n);
    k_agg    <<<(n + 3) / 4, 256, 0, stream>>>(tmp, dinv, row_start, col, b1, hbuf, n);
    k_gemm128<<<(n + 63) / 64, 256, 0, stream>>>(hbuf, W2, tmp, n);
    k_agg    <<<(n + 3) / 4, 256, 0, stream>>>(tmp, dinv, row_start, col, b2, hbuf, n);

    k_pool_partial<<<(n + POOL_ROWS - 1) / POOL_ROWS, 128, 0, stream>>>(hbuf, batch, sums, n);
    k_fc<<<G, 128, 0, stream>>>(sums, batch, Wfc, bfc, out, n);
}

// Round 7
// 195.700 us; speedup vs baseline: 2.3299x; 1.0025x over previous
//
#include <hip/hip_runtime.h>
#include <hip/hip_bf16.h>

#define HD 128   // hidden/feature dim
#define NL 7     // label dim
#define BCAP 6144  // per-bucket stage capacity (avg 4082 for E=800K/196 buckets; +50% headroom)

__device__ __forceinline__ unsigned short f2bf(float f) {
    __hip_bfloat16 b = __float2bfloat16(f);   // RNE
    return *reinterpret_cast<unsigned short*>(&b);
}
__device__ __forceinline__ float bf2f(unsigned short u) {
    unsigned int x = ((unsigned int)u) << 16;
    return __uint_as_float(x);
}

// ---------------- CSR build via bucketed counting sort ----------------

__global__ __launch_bounds__(256) void k_bucket(const int* __restrict__ src,
                                                const int* __restrict__ dst, int E,
                                                int* __restrict__ gbcur,
                                                int* __restrict__ stage, int nb) {
    __shared__ int lh[256];
    __shared__ int gb[256];
    int t = threadIdx.x;
    if (t < nb) lh[t] = 0;
    __syncthreads();

    int e0 = blockIdx.x * 4096;
    int bk[16]; int lr[16]; int rec[16];
    #pragma unroll
    for (int j = 0; j < 16; ++j) {
        int e = e0 + j * 256 + t;
        if (e < E) {
            int d = dst[e];
            int s = src[e];
            bk[j]  = d >> 8;
            rec[j] = ((d & 255) << 16) | s;       // src < 65536
            lr[j]  = atomicAdd(&lh[bk[j]], 1);    // local rank
        } else {
            bk[j] = -1; lr[j] = 0; rec[j] = 0;
        }
    }
    __syncthreads();
    if (t < nb) gb[t] = atomicAdd(&gbcur[t], lh[t]);   // reserve run per bucket
    __syncthreads();
    #pragma unroll
    for (int j = 0; j < 16; ++j) {
        if (bk[j] >= 0) {
            int p = gb[bk[j]] + lr[j];
            if (p < BCAP) stage[bk[j] * BCAP + p] = rec[j];
        }
    }
}

__global__ __launch_bounds__(256) void k_bscan(const int* __restrict__ gbcnt,
                                               int* __restrict__ bbase, int nb,
                                               int* __restrict__ row_start, int n) {
    __shared__ int s[256];
    int t = threadIdx.x;
    int val = (t < nb) ? gbcnt[t] : 0;
    s[t] = val;
    __syncthreads();
    #pragma unroll
    for (int off = 1; off < 256; off <<= 1) {
        int v = (t >= off) ? s[t - off] : 0;
        __syncthreads();
        s[t] += v;
        __syncthreads();
    }
    if (t < nb) bbase[t] = s[t] - val;
    if (t == 255) { bbase[nb] = s[255]; row_start[n] = s[255]; }
}

__global__ __launch_bounds__(256) void k_build(const int* __restrict__ stage,
                                               const int* __restrict__ gbcnt,
                                               const int* __restrict__ bbase,
                                               int* __restrict__ col,
                                               int* __restrict__ row_start,
                                               float* __restrict__ dinv, int n) {
    __shared__ int rec_s[BCAP];
    __shared__ unsigned short rank_s[BCAP];
    __shared__ int hist[256];
    __shared__ int scan_s[256];
    int b = blockIdx.x, t = threadIdx.x;
    int cnt  = min(gbcnt[b], BCAP);
    int base = bbase[b];
    int node0 = b << 8;

    hist[t] = 0;
    __syncthreads();
    for (int e = t; e < cnt; e += 256) {
        int r = stage[b * BCAP + e];
        rec_s[e] = r;
        rank_s[e] = (unsigned short)atomicAdd(&hist[r >> 16], 1);
    }
    __syncthreads();

    int deg = hist[t];
    int node = node0 + t;
    if (node < n) dinv[node] = 1.0f / sqrtf((float)(deg + 1));  // +1 self loop

    scan_s[t] = deg;
    __syncthreads();
    #pragma unroll
    for (int off = 1; off < 256; off <<= 1) {
        int v = (t >= off) ? scan_s[t - off] : 0;
        __syncthreads();
        scan_s[t] += v;
        __syncthreads();
    }
    int lrs = scan_s[t] - deg;      // local exclusive prefix
    hist[t] = lrs;                  // reuse hist as lrs table
    if (node < n) row_start[node] = base + lrs;
    __syncthreads();

    for (int e = t; e < cnt; e += 256) {
        int r = rec_s[e];
        col[base + hist[r >> 16] + rank_s[e]] = r & 0xFFFF;
    }
}

// ---------------- per-edge weight precompute: ecol[e] = {src, dinv[src]*dinv[dst]} ----------
// 16 lanes per node; removes the random dinv gather from the agg hot loop.

__global__ __launch_bounds__(256) void k_wnorm(const int* __restrict__ col,
                                               const int* __restrict__ row_start,
                                               const float* __restrict__ dinv,
                                               int2* __restrict__ ecol, int n) {
    int tid = blockIdx.x * 256 + threadIdx.x;
    int node = tid >> 4;
    int l = tid & 15;
    if (node >= n) return;
    float dv = dinv[node];
    int e1 = row_start[node + 1];
    for (int e = row_start[node] + l; e < e1; e += 16) {
        int s = col[e];
        int2 p;
        p.x = s;
        p.y = __float_as_int(dinv[s] * dv);
        ecol[e] = p;
    }
}

// ---------------- GEMM: Y[n,128](bf16) = X[n,128](f32) @ W[128,128](f32) ----------------

__global__ __launch_bounds__(256) void k_gemm128(const float* __restrict__ X,
                                                 const float* __restrict__ W,
                                                 unsigned short* __restrict__ Y, int n) {
    __shared__ float xs[64][HD];
    int tid = threadIdx.x;
    int row0 = blockIdx.x * 64;

    #pragma unroll
    for (int j = 0; j < 8; ++j) {
        int f4 = tid + j * 256;        // 0..2047
        int r = f4 >> 5;               // 32 float4 per row
        int c = (f4 & 31) * 4;
        int gr = row0 + r;
        float4 v = make_float4(0.f, 0.f, 0.f, 0.f);
        if (gr < n) v = *(const float4*)&X[(size_t)gr * HD + c];
        *(float4*)&xs[r][c] = v;
    }
    __syncthreads();

    int cg = (tid & 31) * 4;
    int rg = (tid >> 5) * 8;

    float4 acc[8];
    #pragma unroll
    for (int i = 0; i < 8; ++i) acc[i] = make_float4(0.f, 0.f, 0.f, 0.f);

    for (int k = 0; k < HD; k += 4) {
        float4 w0 = *(const float4*)&W[(size_t)(k + 0) * HD + cg];
        float4 w1 = *(const float4*)&W[(size_t)(k + 1) * HD + cg];
        float4 w2 = *(const float4*)&W[(size_t)(k + 2) * HD + cg];
        float4 w3 = *(const float4*)&W[(size_t)(k + 3) * HD + cg];
        #pragma unroll
        for (int i = 0; i < 8; ++i) {
            float4 xv = *(const float4*)&xs[rg + i][k];
            acc[i].x = fmaf(xv.x, w0.x, acc[i].x);
            acc[i].y = fmaf(xv.x, w0.y, acc[i].y);
            acc[i].z = fmaf(xv.x, w0.z, acc[i].z);
            acc[i].w = fmaf(xv.x, w0.w, acc[i].w);
            acc[i].x = fmaf(xv.y, w1.x, acc[i].x);
            acc[i].y = fmaf(xv.y, w1.y, acc[i].y);
            acc[i].z = fmaf(xv.y, w1.z, acc[i].z);
            acc[i].w = fmaf(xv.y, w1.w, acc[i].w);
            acc[i].x = fmaf(xv.z, w2.x, acc[i].x);
            acc[i].y = fmaf(xv.z, w2.y, acc[i].y);
            acc[i].z = fmaf(xv.z, w2.z, acc[i].z);
            acc[i].w = fmaf(xv.z, w2.w, acc[i].w);
            acc[i].x = fmaf(xv.w, w3.x, acc[i].x);
            acc[i].y = fmaf(xv.w, w3.y, acc[i].y);
            acc[i].z = fmaf(xv.w, w3.z, acc[i].z);
            acc[i].w = fmaf(xv.w, w3.w, acc[i].w);
        }
    }

    #pragma unroll
    for (int i = 0; i < 8; ++i) {
        int gr = row0 + rg + i;
        if (gr < n) {
            ushort4 o;
            o.x = f2bf(acc[i].x);
            o.y = f2bf(acc[i].y);
            o.z = f2bf(acc[i].z);
            o.w = f2bf(acc[i].w);
            *(ushort4*)&Y[(size_t)gr * HD + cg] = o;
        }
    }
}

// ---------------- Aggregation (bf16 gather, f32 accumulate) ----------------
// Inner loop reads the sequential {src, weight} edge stream (8B/edge, wave-uniform)
// and issues 8 row gathers per iteration; tail is predicated (uniform branch), not serial.

__global__ __launch_bounds__(256) void k_agg(const unsigned short* __restrict__ hin,
                                             const int2* __restrict__ ecol,
                                             const float* __restrict__ dinv,
                                             const int* __restrict__ row_start,
                                             const float* __restrict__ bias,
                                             float* __restrict__ hout, int n) {
    int wave = threadIdx.x >> 6;
    int lane = threadIdx.x & 63;
    int v = blockIdx.x * 4 + wave;
    if (v >= n) return;

    float dv = dinv[v];
    int f = lane * 2;
    ushort2 sv = *(const ushort2*)(hin + (size_t)v * HD + f);
    float selfw = dv * dv;
    float accx = bf2f(sv.x) * selfw;
    float accy = bf2f(sv.y) * selfw;

    int e  = row_start[v];
    int e1 = row_start[v + 1];

    for (; e + 8 <= e1; e += 8) {
        int2 p0 = ecol[e],   p1 = ecol[e+1], p2 = ecol[e+2], p3 = ecol[e+3];
        int2 p4 = ecol[e+4], p5 = ecol[e+5], p6 = ecol[e+6], p7 = ecol[e+7];
        ushort2 a0 = *(const ushort2*)(hin + (size_t)p0.x * HD + f);
        ushort2 a1 = *(const ushort2*)(hin + (size_t)p1.x * HD + f);
        ushort2 a2 = *(const ushort2*)(hin + (size_t)p2.x * HD + f);
        ushort2 a3 = *(const ushort2*)(hin + (size_t)p3.x * HD + f);
        ushort2 a4 = *(const ushort2*)(hin + (size_t)p4.x * HD + f);
        ushort2 a5 = *(const ushort2*)(hin + (size_t)p5.x * HD + f);
        ushort2 a6 = *(const ushort2*)(hin + (size_t)p6.x * HD + f);
        ushort2 a7 = *(const ushort2*)(hin + (size_t)p7.x * HD + f);
        float w0 = __int_as_float(p0.y), w1 = __int_as_float(p1.y);
        float w2 = __int_as_float(p2.y), w3 = __int_as_float(p3.y);
        float w4 = __int_as_float(p4.y), w5 = __int_as_float(p5.y);
        float w6 = __int_as_float(p6.y), w7 = __int_as_float(p7.y);
        accx = fmaf(bf2f(a0.x), w0, accx); accy = fmaf(bf2f(a0.y), w0, accy);
        accx = fmaf(bf2f(a1.x), w1, accx); accy = fmaf(bf2f(a1.y), w1, accy);
        accx = fmaf(bf2f(a2.x), w2, accx); accy = fmaf(bf2f(a2.y), w2, accy);
        accx = fmaf(bf2f(a3.x), w3, accx); accy = fmaf(bf2f(a3.y), w3, accy);
        accx = fmaf(bf2f(a4.x), w4, accx); accy = fmaf(bf2f(a4.y), w4, accy);
        accx = fmaf(bf2f(a5.x), w5, accx); accy = fmaf(bf2f(a5.y), w5, accy);
        accx = fmaf(bf2f(a6.x), w6, accx); accy = fmaf(bf2f(a6.y), w6, accy);
        accx = fmaf(bf2f(a7.x), w7, accx); accy = fmaf(bf2f(a7.y), w7, accy);
    }

    // predicated tail: uniform conditions, loads issue in parallel
    {
        int rem = e1 - e;
        int2 p[7]; ushort2 a[7];
        #pragma unroll
        for (int j = 0; j < 7; ++j) {
            if (j < rem) {
                p[j] = ecol[e + j];
                a[j] = *(const ushort2*)(hin + (size_t)p[j].x * HD + f);
            }
        }
        #pragma unroll
        for (int j = 0; j < 7; ++j) {
            if (j < rem) {
                float w = __int_as_float(p[j].y);
                accx = fmaf(bf2f(a[j].x), w, accx);
                accy = fmaf(bf2f(a[j].y), w, accy);
            }
        }
    }

    float2 b = *(const float2*)(bias + f);
    float2 o;
    o.x = fmaxf(accx + b.x, 0.f);
    o.y = fmaxf(accy + b.y, 0.f);
    *(float2*)(hout + (size_t)v * HD + f) = o;
}

// ---------------- Mean-pool stage 1: per-chunk segmented partial sums ----------------

#define POOL_ROWS 32

__global__ __launch_bounds__(128) void k_pool_partial(const float* __restrict__ h,
                                                      const int* __restrict__ batch,
                                                      float* __restrict__ sums, int n) {
    __shared__ int bs[POOL_ROWS];
    int t = threadIdx.x;
    int r0 = blockIdx.x * POOL_ROWS;
    int r1 = min(r0 + POOL_ROWS, n);
    int cnt = r1 - r0;
    if (t < cnt) bs[t] = batch[r0 + t];
    __syncthreads();

    int g = bs[0];
    float acc = 0.f;
    for (int i = 0; i < cnt; ++i) {
        int bg = bs[i];
        if (bg != g) {
            atomicAdd(&sums[(size_t)g * HD + t], acc);
            acc = 0.f;
            g = bg;
        }
        acc += h[(size_t)(r0 + i) * HD + t];
    }
    atomicAdd(&sums[(size_t)g * HD + t], acc);
}

// ---------------- Mean-pool stage 2: mean + FC ----------------

__global__ __launch_bounds__(128) void k_fc(const float* __restrict__ sums,
                                            const int* __restrict__ batch,
                                            const float* __restrict__ Wfc,
                                            const float* __restrict__ bfc,
                                            float* __restrict__ out, int n) {
    int g = blockIdx.x;
    int t = threadIdx.x;
    __shared__ int slo, shi;
    if (t == 0) {
        int lo = 0, hi = n;
        while (lo < hi) { int m = (lo + hi) >> 1; if (batch[m] < g) lo = m + 1; else hi = m; }
        slo = lo;
        lo = 0; hi = n;
        while (lo < hi) { int m = (lo + hi) >> 1; if (batch[m] < g + 1) lo = m + 1; else hi = m; }
        shi = lo;
    }
    __syncthreads();
    float cnt = (float)(shi - slo);
    __shared__ float sp[HD];
    sp[t] = sums[(size_t)g * HD + t] / fmaxf(cnt, 1.f);
    __syncthreads();
    if (t < NL) {
        float o = bfc[t];
        for (int k = 0; k < HD; ++k) o = fmaf(sp[k], Wfc[k * NL + t], o);
        out[g * NL + t] = o;
    }
}

// ---------------- launch ----------------

extern "C" void kernel_launch(void* const* d_in, const int* in_sizes, int n_in,
                              void* d_out, int out_size, void* d_ws, size_t ws_size,
                              hipStream_t stream) {
    const float* x    = (const float*)d_in[0];
    const int*   ei   = (const int*)d_in[1];
    const int*   batch= (const int*)d_in[2];
    const float* W1   = (const float*)d_in[3];
    const float* b1   = (const float*)d_in[4];
    const float* W2   = (const float*)d_in[5];
    const float* b2   = (const float*)d_in[6];
    const float* Wfc  = (const float*)d_in[7];
    const float* bfc  = (const float*)d_in[8];
    float* out = (float*)d_out;

    int n = in_sizes[0] / HD;       // 50000
    int E = in_sizes[1] / 2;        // 800000
    int G = out_size / NL;          // 128
    const int* srcp = ei;
    const int* dstp = ei + E;

    int nb = (n + 255) >> 8;        // 196 buckets of 256 dst nodes

    char* ws = (char*)d_ws;
    auto align256 = [](size_t v) { return (v + 255) & ~(size_t)255; };
    size_t o = 0;
    int*   row_start = (int*)(ws + o); o = align256(o + (size_t)(n + 1) * 4);
    int*   bbase     = (int*)(ws + o); o = align256(o + (size_t)(nb + 1) * 4);
    int*   gbcur     = (int*)(ws + o); o = align256(o + (size_t)nb * 4);
    float* dinv      = (float*)(ws + o); o = align256(o + (size_t)n * 4);
    int*   col       = (int*)(ws + o); o = align256(o + (size_t)E * 4);
    int2*  ecol      = (int2*)(ws + o); o = align256(o + (size_t)E * 8);
    unsigned short* tmp = (unsigned short*)(ws + o); o = align256(o + (size_t)n * HD * 2);
    float* hbuf      = (float*)(ws + o); o = align256(o + (size_t)n * HD * 4);
    float* sums      = (float*)(ws + o); o = align256(o + (size_t)G * HD * 4);

    // stage aliases hbuf: consumed by k_build before hbuf's first write (k_agg #1)
    int* stage = (int*)hbuf;        // needs nb*BCAP*4 = 4.8MB <= 25.6MB

    hipMemsetAsync(gbcur, 0, (size_t)nb * 4, stream);
    hipMemsetAsync(sums,  0, (size_t)G * HD * 4, stream);

    int nblkC = (E + 4095) / 4096;  // 196
    k_bucket<<<nblkC, 256, 0, stream>>>(srcp, dstp, E, gbcur, stage, nb);
    k_bscan <<<1, 256, 0, stream>>>(gbcur, bbase, nb, row_start, n);
    k_build <<<nb, 256, 0, stream>>>(stage, gbcur, bbase, col, row_start, dinv, n);
    k_wnorm <<<(n * 16 + 255) / 256, 256, 0, stream>>>(col, row_start, dinv, ecol, n);

    k_gemm128<<<(n + 63) / 64, 256, 0, stream>>>(x, W1, tmp, n);
    k_agg    <<<(n + 3) / 4, 256, 0, stream>>>(tmp, ecol, dinv, row_start, b1, hbuf, n);
    k_gemm128<<<(n + 63) / 64, 256, 0, stream>>>(hbuf, W2, tmp, n);
    k_agg    <<<(n + 3) / 4, 256, 0, stream>>>(tmp, ecol, dinv, row_start, b2, hbuf, n);

    k_pool_partial<<<(n + POOL_ROWS - 1) / POOL_ROWS, 128, 0, stream>>>(hbuf, batch, sums, n);
    k_fc<<<G, 128, 0, stream>>>(sums, batch, Wfc, bfc, out, n);
}

// Round 8
// 193.069 us; speedup vs baseline: 2.3617x; 1.0136x over previous
//
#include <hip/hip_runtime.h>
#include <hip/hip_bf16.h>

#define HD 128   // hidden/feature dim
#define NL 7     // label dim
#define BCAP 6144  // per-bucket stage capacity (avg 4082 for E=800K/196 buckets; +50% headroom)

__device__ __forceinline__ unsigned short f2bf(float f) {
    __hip_bfloat16 b = __float2bfloat16(f);   // RNE
    return *reinterpret_cast<unsigned short*>(&b);
}
__device__ __forceinline__ float bf2f(unsigned short u) {
    unsigned int x = ((unsigned int)u) << 16;
    return __uint_as_float(x);
}

// ---------------- workspace zeroing (replaces 2x hipMemsetAsync: each fill
// kernel cost ~40us of launch overhead in the captured graph) ----------------

__global__ __launch_bounds__(256) void k_zero(int* __restrict__ gbcur, int nb,
                                              float* __restrict__ sums, int m) {
    int i = blockIdx.x * 256 + threadIdx.x;
    if (i < nb) gbcur[i] = 0;
    if (i < m) sums[i] = 0.f;
}

// ---------------- CSR build via bucketed counting sort ----------------

__global__ __launch_bounds__(256) void k_bucket(const int* __restrict__ src,
                                                const int* __restrict__ dst, int E,
                                                int* __restrict__ gbcur,
                                                int* __restrict__ stage, int nb) {
    __shared__ int lh[256];
    __shared__ int gb[256];
    int t = threadIdx.x;
    if (t < nb) lh[t] = 0;
    __syncthreads();

    int e0 = blockIdx.x * 4096;
    int bk[16]; int lr[16]; int rec[16];
    #pragma unroll
    for (int j = 0; j < 16; ++j) {
        int e = e0 + j * 256 + t;
        if (e < E) {
            int d = dst[e];
            int s = src[e];
            bk[j]  = d >> 8;
            rec[j] = ((d & 255) << 16) | s;       // src < 65536
            lr[j]  = atomicAdd(&lh[bk[j]], 1);    // local rank
        } else {
            bk[j] = -1; lr[j] = 0; rec[j] = 0;
        }
    }
    __syncthreads();
    if (t < nb) gb[t] = atomicAdd(&gbcur[t], lh[t]);   // reserve run per bucket
    __syncthreads();
    #pragma unroll
    for (int j = 0; j < 16; ++j) {
        if (bk[j] >= 0) {
            int p = gb[bk[j]] + lr[j];
            if (p < BCAP) stage[bk[j] * BCAP + p] = rec[j];
        }
    }
}

__global__ __launch_bounds__(256) void k_bscan(const int* __restrict__ gbcnt,
                                               int* __restrict__ bbase, int nb,
                                               int* __restrict__ row_start, int n) {
    __shared__ int s[256];
    int t = threadIdx.x;
    int val = (t < nb) ? gbcnt[t] : 0;
    s[t] = val;
    __syncthreads();
    #pragma unroll
    for (int off = 1; off < 256; off <<= 1) {
        int v = (t >= off) ? s[t - off] : 0;
        __syncthreads();
        s[t] += v;
        __syncthreads();
    }
    if (t < nb) bbase[t] = s[t] - val;
    if (t == 255) { bbase[nb] = s[255]; row_start[n] = s[255]; }
}

__global__ __launch_bounds__(256) void k_build(const int* __restrict__ stage,
                                               const int* __restrict__ gbcnt,
                                               const int* __restrict__ bbase,
                                               int* __restrict__ col,
                                               int* __restrict__ row_start,
                                               float* __restrict__ dinv, int n) {
    __shared__ int rec_s[BCAP];
    __shared__ unsigned short rank_s[BCAP];
    __shared__ int hist[256];
    __shared__ int scan_s[256];
    int b = blockIdx.x, t = threadIdx.x;
    int cnt  = min(gbcnt[b], BCAP);
    int base = bbase[b];
    int node0 = b << 8;

    hist[t] = 0;
    __syncthreads();
    for (int e = t; e < cnt; e += 256) {
        int r = stage[b * BCAP + e];
        rec_s[e] = r;
        rank_s[e] = (unsigned short)atomicAdd(&hist[r >> 16], 1);
    }
    __syncthreads();

    int deg = hist[t];
    int node = node0 + t;
    if (node < n) dinv[node] = 1.0f / sqrtf((float)(deg + 1));  // +1 self loop

    scan_s[t] = deg;
    __syncthreads();
    #pragma unroll
    for (int off = 1; off < 256; off <<= 1) {
        int v = (t >= off) ? scan_s[t - off] : 0;
        __syncthreads();
        scan_s[t] += v;
        __syncthreads();
    }
    int lrs = scan_s[t] - deg;      // local exclusive prefix
    hist[t] = lrs;                  // reuse hist as lrs table
    if (node < n) row_start[node] = base + lrs;
    __syncthreads();

    for (int e = t; e < cnt; e += 256) {
        int r = rec_s[e];
        col[base + hist[r >> 16] + rank_s[e]] = r & 0xFFFF;
    }
}

// ---------------- per-edge weight precompute: ecol[e] = {src, dinv[src]*dinv[dst]} ----------

__global__ __launch_bounds__(256) void k_wnorm(const int* __restrict__ col,
                                               const int* __restrict__ row_start,
                                               const float* __restrict__ dinv,
                                               int2* __restrict__ ecol, int n) {
    int tid = blockIdx.x * 256 + threadIdx.x;
    int node = tid >> 4;
    int l = tid & 15;
    if (node >= n) return;
    float dv = dinv[node];
    int e1 = row_start[node + 1];
    for (int e = row_start[node] + l; e < e1; e += 16) {
        int s = col[e];
        int2 p;
        p.x = s;
        p.y = __float_as_int(dinv[s] * dv);
        ecol[e] = p;
    }
}

// ---------------- GEMM: Y[n,128](bf16) = X[n,128](f32) @ W[128,128](f32) ----------------

__global__ __launch_bounds__(256) void k_gemm128(const float* __restrict__ X,
                                                 const float* __restrict__ W,
                                                 unsigned short* __restrict__ Y, int n) {
    __shared__ float xs[64][HD];
    int tid = threadIdx.x;
    int row0 = blockIdx.x * 64;

    #pragma unroll
    for (int j = 0; j < 8; ++j) {
        int f4 = tid + j * 256;        // 0..2047
        int r = f4 >> 5;               // 32 float4 per row
        int c = (f4 & 31) * 4;
        int gr = row0 + r;
        float4 v = make_float4(0.f, 0.f, 0.f, 0.f);
        if (gr < n) v = *(const float4*)&X[(size_t)gr * HD + c];
        *(float4*)&xs[r][c] = v;
    }
    __syncthreads();

    int cg = (tid & 31) * 4;
    int rg = (tid >> 5) * 8;

    float4 acc[8];
    #pragma unroll
    for (int i = 0; i < 8; ++i) acc[i] = make_float4(0.f, 0.f, 0.f, 0.f);

    for (int k = 0; k < HD; k += 4) {
        float4 w0 = *(const float4*)&W[(size_t)(k + 0) * HD + cg];
        float4 w1 = *(const float4*)&W[(size_t)(k + 1) * HD + cg];
        float4 w2 = *(const float4*)&W[(size_t)(k + 2) * HD + cg];
        float4 w3 = *(const float4*)&W[(size_t)(k + 3) * HD + cg];
        #pragma unroll
        for (int i = 0; i < 8; ++i) {
            float4 xv = *(const float4*)&xs[rg + i][k];
            acc[i].x = fmaf(xv.x, w0.x, acc[i].x);
            acc[i].y = fmaf(xv.x, w0.y, acc[i].y);
            acc[i].z = fmaf(xv.x, w0.z, acc[i].z);
            acc[i].w = fmaf(xv.x, w0.w, acc[i].w);
            acc[i].x = fmaf(xv.y, w1.x, acc[i].x);
            acc[i].y = fmaf(xv.y, w1.y, acc[i].y);
            acc[i].z = fmaf(xv.y, w1.z, acc[i].z);
            acc[i].w = fmaf(xv.y, w1.w, acc[i].w);
            acc[i].x = fmaf(xv.z, w2.x, acc[i].x);
            acc[i].y = fmaf(xv.z, w2.y, acc[i].y);
            acc[i].z = fmaf(xv.z, w2.z, acc[i].z);
            acc[i].w = fmaf(xv.z, w2.w, acc[i].w);
            acc[i].x = fmaf(xv.w, w3.x, acc[i].x);
            acc[i].y = fmaf(xv.w, w3.y, acc[i].y);
            acc[i].z = fmaf(xv.w, w3.z, acc[i].z);
            acc[i].w = fmaf(xv.w, w3.w, acc[i].w);
        }
    }

    #pragma unroll
    for (int i = 0; i < 8; ++i) {
        int gr = row0 + rg + i;
        if (gr < n) {
            ushort4 o;
            o.x = f2bf(acc[i].x);
            o.y = f2bf(acc[i].y);
            o.z = f2bf(acc[i].z);
            o.w = f2bf(acc[i].w);
            *(ushort4*)&Y[(size_t)gr * HD + cg] = o;
        }
    }
}

// ---------------- Aggregation (bf16 gather, f32 accumulate) ----------------

__global__ __launch_bounds__(256) void k_agg(const unsigned short* __restrict__ hin,
                                             const int2* __restrict__ ecol,
                                             const float* __restrict__ dinv,
                                             const int* __restrict__ row_start,
                                             const float* __restrict__ bias,
                                             float* __restrict__ hout, int n) {
    int wave = threadIdx.x >> 6;
    int lane = threadIdx.x & 63;
    int v = blockIdx.x * 4 + wave;
    if (v >= n) return;

    float dv = dinv[v];
    int f = lane * 2;
    ushort2 sv = *(const ushort2*)(hin + (size_t)v * HD + f);
    float selfw = dv * dv;
    float accx = bf2f(sv.x) * selfw;
    float accy = bf2f(sv.y) * selfw;

    int e  = row_start[v];
    int e1 = row_start[v + 1];

    for (; e + 8 <= e1; e += 8) {
        int2 p0 = ecol[e],   p1 = ecol[e+1], p2 = ecol[e+2], p3 = ecol[e+3];
        int2 p4 = ecol[e+4], p5 = ecol[e+5], p6 = ecol[e+6], p7 = ecol[e+7];
        ushort2 a0 = *(const ushort2*)(hin + (size_t)p0.x * HD + f);
        ushort2 a1 = *(const ushort2*)(hin + (size_t)p1.x * HD + f);
        ushort2 a2 = *(const ushort2*)(hin + (size_t)p2.x * HD + f);
        ushort2 a3 = *(const ushort2*)(hin + (size_t)p3.x * HD + f);
        ushort2 a4 = *(const ushort2*)(hin + (size_t)p4.x * HD + f);
        ushort2 a5 = *(const ushort2*)(hin + (size_t)p5.x * HD + f);
        ushort2 a6 = *(const ushort2*)(hin + (size_t)p6.x * HD + f);
        ushort2 a7 = *(const ushort2*)(hin + (size_t)p7.x * HD + f);
        float w0 = __int_as_float(p0.y), w1 = __int_as_float(p1.y);
        float w2 = __int_as_float(p2.y), w3 = __int_as_float(p3.y);
        float w4 = __int_as_float(p4.y), w5 = __int_as_float(p5.y);
        float w6 = __int_as_float(p6.y), w7 = __int_as_float(p7.y);
        accx = fmaf(bf2f(a0.x), w0, accx); accy = fmaf(bf2f(a0.y), w0, accy);
        accx = fmaf(bf2f(a1.x), w1, accx); accy = fmaf(bf2f(a1.y), w1, accy);
        accx = fmaf(bf2f(a2.x), w2, accx); accy = fmaf(bf2f(a2.y), w2, accy);
        accx = fmaf(bf2f(a3.x), w3, accx); accy = fmaf(bf2f(a3.y), w3, accy);
        accx = fmaf(bf2f(a4.x), w4, accx); accy = fmaf(bf2f(a4.y), w4, accy);
        accx = fmaf(bf2f(a5.x), w5, accx); accy = fmaf(bf2f(a5.y), w5, accy);
        accx = fmaf(bf2f(a6.x), w6, accx); accy = fmaf(bf2f(a6.y), w6, accy);
        accx = fmaf(bf2f(a7.x), w7, accx); accy = fmaf(bf2f(a7.y), w7, accy);
    }

    // predicated tail: uniform conditions, loads issue in parallel
    {
        int rem = e1 - e;
        int2 p[7]; ushort2 a[7];
        #pragma unroll
        for (int j = 0; j < 7; ++j) {
            if (j < rem) {
                p[j] = ecol[e + j];
                a[j] = *(const ushort2*)(hin + (size_t)p[j].x * HD + f);
            }
        }
        #pragma unroll
        for (int j = 0; j < 7; ++j) {
            if (j < rem) {
                float w = __int_as_float(p[j].y);
                accx = fmaf(bf2f(a[j].x), w, accx);
                accy = fmaf(bf2f(a[j].y), w, accy);
            }
        }
    }

    float2 b = *(const float2*)(bias + f);
    float2 o;
    o.x = fmaxf(accx + b.x, 0.f);
    o.y = fmaxf(accy + b.y, 0.f);
    *(float2*)(hout + (size_t)v * HD + f) = o;
}

// ---------------- Mean-pool stage 1: per-chunk segmented partial sums ----------------

#define POOL_ROWS 32

__global__ __launch_bounds__(128) void k_pool_partial(const float* __restrict__ h,
                                                      const int* __restrict__ batch,
                                                      float* __restrict__ sums, int n) {
    __shared__ int bs[POOL_ROWS];
    int t = threadIdx.x;
    int r0 = blockIdx.x * POOL_ROWS;
    int r1 = min(r0 + POOL_ROWS, n);
    int cnt = r1 - r0;
    if (t < cnt) bs[t] = batch[r0 + t];
    __syncthreads();

    int g = bs[0];
    float acc = 0.f;
    for (int i = 0; i < cnt; ++i) {
        int bg = bs[i];
        if (bg != g) {
            atomicAdd(&sums[(size_t)g * HD + t], acc);
            acc = 0.f;
            g = bg;
        }
        acc += h[(size_t)(r0 + i) * HD + t];
    }
    atomicAdd(&sums[(size_t)g * HD + t], acc);
}

// ---------------- Mean-pool stage 2: mean + FC ----------------

__global__ __launch_bounds__(128) void k_fc(const float* __restrict__ sums,
                                            const int* __restrict__ batch,
                                            const float* __restrict__ Wfc,
                                            const float* __restrict__ bfc,
                                            float* __restrict__ out, int n) {
    int g = blockIdx.x;
    int t = threadIdx.x;
    __shared__ int slo, shi;
    if (t == 0) {
        int lo = 0, hi = n;
        while (lo < hi) { int m = (lo + hi) >> 1; if (batch[m] < g) lo = m + 1; else hi = m; }
        slo = lo;
        lo = 0; hi = n;
        while (lo < hi) { int m = (lo + hi) >> 1; if (batch[m] < g + 1) lo = m + 1; else hi = m; }
        shi = lo;
    }
    __syncthreads();
    float cnt = (float)(shi - slo);
    __shared__ float sp[HD];
    sp[t] = sums[(size_t)g * HD + t] / fmaxf(cnt, 1.f);
    __syncthreads();
    if (t < NL) {
        float o = bfc[t];
        for (int k = 0; k < HD; ++k) o = fmaf(sp[k], Wfc[k * NL + t], o);
        out[g * NL + t] = o;
    }
}

// ---------------- launch ----------------

extern "C" void kernel_launch(void* const* d_in, const int* in_sizes, int n_in,
                              void* d_out, int out_size, void* d_ws, size_t ws_size,
                              hipStream_t stream) {
    const float* x    = (const float*)d_in[0];
    const int*   ei   = (const int*)d_in[1];
    const int*   batch= (const int*)d_in[2];
    const float* W1   = (const float*)d_in[3];
    const float* b1   = (const float*)d_in[4];
    const float* W2   = (const float*)d_in[5];
    const float* b2   = (const float*)d_in[6];
    const float* Wfc  = (const float*)d_in[7];
    const float* bfc  = (const float*)d_in[8];
    float* out = (float*)d_out;

    int n = in_sizes[0] / HD;       // 50000
    int E = in_sizes[1] / 2;        // 800000
    int G = out_size / NL;          // 128
    const int* srcp = ei;
    const int* dstp = ei + E;

    int nb = (n + 255) >> 8;        // 196 buckets of 256 dst nodes

    char* ws = (char*)d_ws;
    auto align256 = [](size_t v) { return (v + 255) & ~(size_t)255; };
    size_t o = 0;
    int*   row_start = (int*)(ws + o); o = align256(o + (size_t)(n + 1) * 4);
    int*   bbase     = (int*)(ws + o); o = align256(o + (size_t)(nb + 1) * 4);
    int*   gbcur     = (int*)(ws + o); o = align256(o + (size_t)nb * 4);
    float* dinv      = (float*)(ws + o); o = align256(o + (size_t)n * 4);
    int*   col       = (int*)(ws + o); o = align256(o + (size_t)E * 4);
    int2*  ecol      = (int2*)(ws + o); o = align256(o + (size_t)E * 8);
    unsigned short* tmp = (unsigned short*)(ws + o); o = align256(o + (size_t)n * HD * 2);
    float* hbuf      = (float*)(ws + o); o = align256(o + (size_t)n * HD * 4);
    float* sums      = (float*)(ws + o); o = align256(o + (size_t)G * HD * 4);

    // stage aliases hbuf: consumed by k_build before hbuf's first write (k_agg #1)
    int* stage = (int*)hbuf;        // needs nb*BCAP*4 = 4.8MB <= 25.6MB

    int mZero = G * HD;             // 16384 floats of sums
    k_zero<<<(mZero + 255) / 256, 256, 0, stream>>>(gbcur, nb, sums, mZero);

    int nblkC = (E + 4095) / 4096;  // 196
    k_bucket<<<nblkC, 256, 0, stream>>>(srcp, dstp, E, gbcur, stage, nb);
    k_bscan <<<1, 256, 0, stream>>>(gbcur, bbase, nb, row_start, n);
    k_build <<<nb, 256, 0, stream>>>(stage, gbcur, bbase, col, row_start, dinv, n);
    k_wnorm <<<(n * 16 + 255) / 256, 256, 0, stream>>>(col, row_start, dinv, ecol, n);

    k_gemm128<<<(n + 63) / 64, 256, 0, stream>>>(x, W1, tmp, n);
    k_agg    <<<(n + 3) / 4, 256, 0, stream>>>(tmp, ecol, dinv, row_start, b1, hbuf, n);
    k_gemm128<<<(n + 63) / 64, 256, 0, stream>>>(hbuf, W2, tmp, n);
    k_agg    <<<(n + 3) / 4, 256, 0, stream>>>(tmp, ecol, dinv, row_start, b2, hbuf, n);

    k_pool_partial<<<(n + POOL_ROWS - 1) / POOL_ROWS, 128, 0, stream>>>(hbuf, batch, sums, n);
    k_fc<<<G, 128, 0, stream>>>(sums, batch, Wfc, bfc, out, n);
}